// Round 1
// baseline (1289.690 us; speedup 1.0000x reference)
//
#include <hip/hip_runtime.h>

#define LSEQ 2048
#define DMOD 1024
#define NH   4
#define DH   256
#define NCH  64
#define CPAD 260   // 256 + 4 pad: row stride 65 16B-units -> spreads bank-quads

typedef unsigned short u16;

__device__ __forceinline__ float sigf(float x){ return 1.0f/(1.0f + expf(-x)); }

// ---------------- GEMM: C[M][N] = A[M][K] @ B[N][K]^T  (fp32) ----------------
// 64x64 tile, BK=16, 256 threads, 4x4 register blocking, k-major LDS.
__global__ __launch_bounds__(256) void gemm_f32(
    const float* __restrict__ A, const float* __restrict__ B,
    float* __restrict__ C, int M, int N, int K)
{
  __shared__ float As[16][68];
  __shared__ float Bs[16][68];
  const int i0 = blockIdx.x*64, j0 = blockIdx.y*64;
  const int t  = threadIdx.x;
  const int tx = t & 15, ty = t >> 4;
  const int sr = t >> 2, sk = (t & 3)*4;
  float acc[4][4] = {};
  for (int k0 = 0; k0 < K; k0 += 16){
    float4 av = *(const float4*)(A + (size_t)(i0+sr)*K + k0 + sk);
    float4 bv = *(const float4*)(B + (size_t)(j0+sr)*K + k0 + sk);
    __syncthreads();
    As[sk+0][sr] = av.x; As[sk+1][sr] = av.y; As[sk+2][sr] = av.z; As[sk+3][sr] = av.w;
    Bs[sk+0][sr] = bv.x; Bs[sk+1][sr] = bv.y; Bs[sk+2][sr] = bv.z; Bs[sk+3][sr] = bv.w;
    __syncthreads();
    #pragma unroll
    for (int kk = 0; kk < 16; kk++){
      float4 a4 = *(const float4*)&As[kk][ty*4];
      float4 b4 = *(const float4*)&Bs[kk][tx*4];
      acc[0][0] += a4.x*b4.x; acc[0][1] += a4.x*b4.y; acc[0][2] += a4.x*b4.z; acc[0][3] += a4.x*b4.w;
      acc[1][0] += a4.y*b4.x; acc[1][1] += a4.y*b4.y; acc[1][2] += a4.y*b4.z; acc[1][3] += a4.y*b4.w;
      acc[2][0] += a4.z*b4.x; acc[2][1] += a4.z*b4.y; acc[2][2] += a4.z*b4.z; acc[2][3] += a4.z*b4.w;
      acc[3][0] += a4.w*b4.x; acc[3][1] += a4.w*b4.y; acc[3][2] += a4.w*b4.z; acc[3][3] += a4.w*b4.w;
    }
  }
  #pragma unroll
  for (int x=0;x<4;x++){
    #pragma unroll
    for (int y=0;y<4;y++){
      C[(size_t)(i0+ty*4+x)*N + (j0+tx*4+y)] = acc[x][y];
    }
  }
}

// ---------------- depthwise causal conv (K=4) + silu ----------------
// y[i][c] = silu( sum_j x[i-3+j][c] * w[c][j] )
__global__ __launch_bounds__(256) void conv_silu(
    const float* __restrict__ x, const float* __restrict__ w, float* __restrict__ y)
{
  const int idx = blockIdx.x*256 + threadIdx.x;
  const int c = idx & (DMOD-1);
  const int i = idx >> 10;
  float4 wc = *(const float4*)(w + (size_t)c*4);
  float acc = wc.w * x[idx];
  if (i >= 1) acc += wc.z * x[idx -   DMOD];
  if (i >= 2) acc += wc.y * x[idx - 2*DMOD];
  if (i >= 3) acc += wc.x * x[idx - 3*DMOD];
  y[idx] = acc * sigf(acc);
}

// ---------------- beta (sigmoid) + 5-way gate probs per row ----------------
__global__ __launch_bounds__(256) void beta_gate(
    const float* __restrict__ hidden, const float* __restrict__ Wb,
    const float* __restrict__ gw, const float* __restrict__ gb,
    const float* __restrict__ logtemp, const float* __restrict__ epsp,
    float* __restrict__ betab, float* __restrict__ probs)
{
  const int i = blockIdx.x, t = threadIdx.x;
  float4 h4 = *(const float4*)(hidden + (size_t)i*DMOD + t*4);
  float part[24];
  #pragma unroll
  for (int o=0;o<24;o++){
    const float* wr = (o<4) ? (Wb + (size_t)o*DMOD) : (gw + (size_t)(o-4)*DMOD);
    float4 w4 = *(const float4*)(wr + t*4);
    part[o] = h4.x*w4.x + h4.y*w4.y + h4.z*w4.z + h4.w*w4.w;
  }
  __shared__ float red[24][4];
  __shared__ float fin[24];
  const int lane = t & 63, wv = t >> 6;
  #pragma unroll
  for (int o=0;o<24;o++){
    float vv = part[o];
    #pragma unroll
    for (int m=1;m<64;m<<=1) vv += __shfl_xor(vv, m, 64);
    if (lane == 0) red[o][wv] = vv;
  }
  __syncthreads();
  if (t < 24) fin[t] = red[t][0]+red[t][1]+red[t][2]+red[t][3];
  __syncthreads();
  if (t < NH){
    const int hh = t;
    betab[(size_t)i*NH + hh] = sigf(fin[hh]);
    float temp = expf(logtemp[hh]);
    float lg[5], mx = -1e30f;
    #pragma unroll
    for (int p=0;p<5;p++){ lg[p] = (fin[4+hh*5+p] + gb[hh*5+p]) / temp; mx = fmaxf(mx, lg[p]); }
    float ex[5], s = 0.f;
    #pragma unroll
    for (int p=0;p<5;p++){ ex[p] = expf(lg[p]-mx); s += ex[p]; }
    float eps = fminf(fmaxf(epsp[hh], 0.f), 0.2f);
    #pragma unroll
    for (int p=0;p<5;p++) probs[((size_t)i*NH+hh)*5 + p] = (ex[p]/s)*(1.f-5.f*eps) + eps;
  }
}

// ---------------- delta precompute: per (chunk, head) ----------------
// l2norm q,k (written back in place), M = I + strict_lower(diag(beta) k k^T),
// T = M^-1, w = T@(beta*k), u = T@(beta*v), attn = tril(q k^T).
__global__ __launch_bounds__(256) void delta_pre(
    float* __restrict__ q, float* __restrict__ k, const float* __restrict__ v,
    const float* __restrict__ beta, float* __restrict__ wbuf,
    float* __restrict__ ubuf, float* __restrict__ attnb)
{
  const int n = blockIdx.x, h = blockIdx.y;
  const int t = threadIdx.x;
  __shared__ float q_s[32][CPAD], k_s[32][CPAD], v_s[32][CPAD];
  __shared__ float T_s[32][32], Tb_s[32][32], M_s[32][32];
  __shared__ float rr[2][32][8];
  __shared__ float scl[2][32];
  __shared__ float bet_s[32];

  const int row = t >> 3, cq = t & 7;
  const size_t gb = (size_t)(n*32+row)*DMOD + h*DH + cq*32;
  float psq = 0.f, psk = 0.f;
  #pragma unroll
  for (int x=0;x<8;x++){
    float4 qa = *(const float4*)(q + gb + x*4);
    float4 ka = *(const float4*)(k + gb + x*4);
    float4 va = *(const float4*)(v + gb + x*4);
    *(float4*)&q_s[row][cq*32+x*4] = qa;
    *(float4*)&k_s[row][cq*32+x*4] = ka;
    *(float4*)&v_s[row][cq*32+x*4] = va;
    psq += qa.x*qa.x+qa.y*qa.y+qa.z*qa.z+qa.w*qa.w;
    psk += ka.x*ka.x+ka.y*ka.y+ka.z*ka.z+ka.w*ka.w;
  }
  rr[0][row][cq] = psq; rr[1][row][cq] = psk;
  if (t < 32) bet_s[t] = beta[(size_t)(n*32+t)*NH + h];
  __syncthreads();
  if (t < 64){
    const int wh = t >> 5, r = t & 31;
    float s = 1e-6f;
    #pragma unroll
    for (int x=0;x<8;x++) s += rr[wh][r][x];
    scl[wh][r] = rsqrtf(s);
  }
  __syncthreads();
  {
    const float sq = scl[0][row], sk2 = scl[1][row];
    #pragma unroll
    for (int x=0;x<8;x++){
      float4 qa = *(float4*)&q_s[row][cq*32+x*4];
      qa.x*=sq; qa.y*=sq; qa.z*=sq; qa.w*=sq;
      *(float4*)&q_s[row][cq*32+x*4] = qa;
      *(float4*)(q + gb + x*4) = qa;
      float4 ka = *(float4*)&k_s[row][cq*32+x*4];
      ka.x*=sk2; ka.y*=sk2; ka.z*=sk2; ka.w*=sk2;
      *(float4*)&k_s[row][cq*32+x*4] = ka;
      *(float4*)(k + gb + x*4) = ka;
    }
  }
  __syncthreads();
  // M matrix
  {
    const int c = t >> 3, m0 = (t & 7)*4;
    float d0=0.f,d1=0.f,d2=0.f,d3=0.f;
    for (int kk=0;kk<DH;kk+=4){
      float4 a  = *(const float4*)&k_s[c][kk];
      float4 b0 = *(const float4*)&k_s[m0+0][kk];
      float4 b1 = *(const float4*)&k_s[m0+1][kk];
      float4 b2 = *(const float4*)&k_s[m0+2][kk];
      float4 b3 = *(const float4*)&k_s[m0+3][kk];
      d0 += a.x*b0.x + a.y*b0.y + a.z*b0.z + a.w*b0.w;
      d1 += a.x*b1.x + a.y*b1.y + a.z*b1.z + a.w*b1.w;
      d2 += a.x*b2.x + a.y*b2.y + a.z*b2.z + a.w*b2.w;
      d3 += a.x*b3.x + a.y*b3.y + a.z*b3.z + a.w*b3.w;
    }
    const float bc = bet_s[c];
    M_s[c][m0+0] = (m0+0 < c) ? bc*d0 : ((m0+0==c)?1.f:0.f);
    M_s[c][m0+1] = (m0+1 < c) ? bc*d1 : ((m0+1==c)?1.f:0.f);
    M_s[c][m0+2] = (m0+2 < c) ? bc*d2 : ((m0+2==c)?1.f:0.f);
    M_s[c][m0+3] = (m0+3 < c) ? bc*d3 : ((m0+3==c)?1.f:0.f);
  }
  __syncthreads();
  // T = M^-1 via forward substitution; column j owned by lane j (no cross-lane deps)
  if (t < 32){
    const int j = t;
    for (int c=0;c<32;c++){
      float s = (c==j) ? 1.f : 0.f;
      for (int m=0;m<c;m++) s -= M_s[c][m]*T_s[m][j];
      T_s[c][j] = s;
    }
  }
  __syncthreads();
  {
    const int c = t >> 3, m0 = (t & 7)*4;
    #pragma unroll
    for (int x=0;x<4;x++) Tb_s[c][m0+x] = T_s[c][m0+x]*bet_s[m0+x];
  }
  __syncthreads();
  // w = Tb @ k_s ; u = Tb @ v_s   (interleaved-column mapping for quad spread)
  {
    const int colb = (t & 7)*4;   // thread covers cols colb + y*32
    float4 aw[8] = {};
    float4 au[8] = {};
    for (int m=0;m<32;m++){
      const float tb = Tb_s[row][m];
      #pragma unroll
      for (int y=0;y<8;y++){
        float4 kv = *(const float4*)&k_s[m][colb + y*32];
        float4 vv = *(const float4*)&v_s[m][colb + y*32];
        aw[y].x += tb*kv.x; aw[y].y += tb*kv.y; aw[y].z += tb*kv.z; aw[y].w += tb*kv.w;
        au[y].x += tb*vv.x; au[y].y += tb*vv.y; au[y].z += tb*vv.z; au[y].w += tb*vv.w;
      }
    }
    const size_t ob = (size_t)(n*32+row)*DMOD + h*DH + colb;
    #pragma unroll
    for (int y=0;y<8;y++){
      *(float4*)(wbuf + ob + y*32) = aw[y];
      *(float4*)(ubuf + ob + y*32) = au[y];
    }
  }
  // attn = tril(q k^T)
  {
    const int c = t >> 3, m0 = (t & 7)*4;
    float d0=0.f,d1=0.f,d2=0.f,d3=0.f;
    for (int kk=0;kk<DH;kk+=4){
      float4 a  = *(const float4*)&q_s[c][kk];
      float4 b0 = *(const float4*)&k_s[m0+0][kk];
      float4 b1 = *(const float4*)&k_s[m0+1][kk];
      float4 b2 = *(const float4*)&k_s[m0+2][kk];
      float4 b3 = *(const float4*)&k_s[m0+3][kk];
      d0 += a.x*b0.x + a.y*b0.y + a.z*b0.z + a.w*b0.w;
      d1 += a.x*b1.x + a.y*b1.y + a.z*b1.z + a.w*b1.w;
      d2 += a.x*b2.x + a.y*b2.y + a.z*b2.z + a.w*b2.w;
      d3 += a.x*b3.x + a.y*b3.y + a.z*b3.z + a.w*b3.w;
    }
    const size_t ab = (size_t)(h*NCH+n)*1024 + (size_t)c*32;
    attnb[ab + m0+0] = (m0+0 <= c) ? d0 : 0.f;
    attnb[ab + m0+1] = (m0+1 <= c) ? d1 : 0.f;
    attnb[ab + m0+2] = (m0+2 <= c) ? d2 : 0.f;
    attnb[ab + m0+3] = (m0+3 <= c) ? d3 : 0.f;
  }
}

// ---------------- delta scan: sequential over 64 chunks ----------------
// grid (8 dv-tiles, 4 heads), 512 threads, S^T [32 dv][256 dk] in LDS.
__global__ __launch_bounds__(512) void delta_scan(
    const float* __restrict__ q, const float* __restrict__ k,
    const float* __restrict__ wbuf, const float* __restrict__ ubuf,
    const float* __restrict__ attnb, float* __restrict__ dout)
{
  const int jt = blockIdx.x, h = blockIdx.y;
  const int j0 = jt*32;
  const int t = threadIdx.x;
  __shared__ float S_t[32][CPAD];
  __shared__ float q_s[32][CPAD], k_s[32][CPAD], w_s[32][CPAD];
  __shared__ float u_s[32][32], ua_s[32][32], at_s[32][32];
  for (int i=t; i<32*CPAD; i+=512) (&S_t[0][0])[i] = 0.f;

  const int srow = t >> 4, scq = t & 15;       // staging map
  const int j1 = t & 31;                       // dv within tile
  const int cp = t >> 5;                       // 0..15
  const int c0 = cp, c1 = cp + 16;             // the two chunk-rows this thread handles
  const int dkb = (t >> 5)*16;                 // dk segment for S update

  for (int n=0;n<NCH;n++){
    __syncthreads();   // prev-iter phase2 done (and S_t init visible on n=0)
    {
      const size_t gbs = (size_t)(n*32+srow)*DMOD + h*DH + scq*16;
      #pragma unroll
      for (int x=0;x<4;x++){
        *(float4*)&q_s[srow][scq*16+x*4] = *(const float4*)(q    + gbs + x*4);
        *(float4*)&k_s[srow][scq*16+x*4] = *(const float4*)(k    + gbs + x*4);
        *(float4*)&w_s[srow][scq*16+x*4] = *(const float4*)(wbuf + gbs + x*4);
      }
      const int cc = t >> 5, jj = t & 31;
      u_s[cc   ][jj] = ubuf[(size_t)(n*32+cc   )*DMOD + h*DH + j0 + jj];
      u_s[cc+16][jj] = ubuf[(size_t)(n*32+cc+16)*DMOD + h*DH + j0 + jj];
      (&at_s[0][0])[t]     = attnb[(size_t)(h*NCH+n)*1024 + t];
      (&at_s[0][0])[t+512] = attnb[(size_t)(h*NCH+n)*1024 + t + 512];
    }
    __syncthreads();
    // phase 1: u_adj = u - w@S  and partial o = q@S (same S pass)
    float a0 = u_s[c0][j1], a1 = u_s[c1][j1];
    float o0 = 0.f, o1 = 0.f;
    #pragma unroll 4
    for (int dk=0; dk<DH; dk+=4){
      float4 s4 = *(const float4*)&S_t[j1][dk];
      float4 w0 = *(const float4*)&w_s[c0][dk];
      float4 w1 = *(const float4*)&w_s[c1][dk];
      float4 q0 = *(const float4*)&q_s[c0][dk];
      float4 q1 = *(const float4*)&q_s[c1][dk];
      a0 -= w0.x*s4.x + w0.y*s4.y + w0.z*s4.z + w0.w*s4.w;
      a1 -= w1.x*s4.x + w1.y*s4.y + w1.z*s4.z + w1.w*s4.w;
      o0 += q0.x*s4.x + q0.y*s4.y + q0.z*s4.z + q0.w*s4.w;
      o1 += q1.x*s4.x + q1.y*s4.y + q1.z*s4.z + q1.w*s4.w;
    }
    ua_s[c0][j1] = a0; ua_s[c1][j1] = a1;
    __syncthreads();
    // phase 2a: o += attn @ u_adj ; write out
    for (int m=0;m<32;m++){
      const float uv = ua_s[m][j1];
      o0 += at_s[c0][m]*uv;
      o1 += at_s[c1][m]*uv;
    }
    dout[(size_t)(n*32+c0)*DMOD + h*DH + j0 + j1] = o0;
    dout[(size_t)(n*32+c1)*DMOD + h*DH + j0 + j1] = o1;
    // phase 2b: S += k^T @ u_adj   (each (j1,dkb) owned by one thread)
    {
      float4 s0 = *(float4*)&S_t[j1][dkb+0];
      float4 s1 = *(float4*)&S_t[j1][dkb+4];
      float4 s2 = *(float4*)&S_t[j1][dkb+8];
      float4 s3 = *(float4*)&S_t[j1][dkb+12];
      for (int c=0;c<32;c++){
        const float uv = ua_s[c][j1];
        float4 k0v = *(const float4*)&k_s[c][dkb+0];
        float4 k1v = *(const float4*)&k_s[c][dkb+4];
        float4 k2v = *(const float4*)&k_s[c][dkb+8];
        float4 k3v = *(const float4*)&k_s[c][dkb+12];
        s0.x += uv*k0v.x; s0.y += uv*k0v.y; s0.z += uv*k0v.z; s0.w += uv*k0v.w;
        s1.x += uv*k1v.x; s1.y += uv*k1v.y; s1.z += uv*k1v.z; s1.w += uv*k1v.w;
        s2.x += uv*k2v.x; s2.y += uv*k2v.y; s2.z += uv*k2v.z; s2.w += uv*k2v.w;
        s3.x += uv*k3v.x; s3.y += uv*k3v.y; s3.z += uv*k3v.z; s3.w += uv*k3v.w;
      }
      *(float4*)&S_t[j1][dkb+0]  = s0;
      *(float4*)&S_t[j1][dkb+4]  = s1;
      *(float4*)&S_t[j1][dkb+8]  = s2;
      *(float4*)&S_t[j1][dkb+12] = s3;
    }
  }
}

// ---------------- transpose FIR filters to [j][c] for coalesced reads ----------------
__global__ void prep_fir(const float* __restrict__ fs, const float* __restrict__ fm,
                         const float* __restrict__ fl, float* __restrict__ fts,
                         float* __restrict__ ftm, float* __restrict__ ftl)
{
  const int idx = blockIdx.x*256 + threadIdx.x;
  if (idx < 63*1024){
    const int j = idx >> 10, c = idx & 1023;
    ftl[idx] = fl[(size_t)c*63 + j];
  } else if (idx < 78*1024){
    const int r = idx - 63*1024;
    const int j = r >> 10, c = r & 1023;
    ftm[r] = fm[(size_t)c*15 + j];
  } else {
    const int r = idx - 78*1024;
    const int j = r >> 10, c = r & 1023;
    fts[r] = fs[(size_t)c*3 + j];
  }
}

// ---------------- FIR convs + 5-way gated mix + per-head RMSNorm ----------------
__global__ __launch_bounds__(256) void fir_mix(
    const float* __restrict__ v, const float* __restrict__ dout,
    const float* __restrict__ probs, const float* __restrict__ ftl,
    const float* __restrict__ ftm, const float* __restrict__ fts,
    const float* __restrict__ normw, float* __restrict__ omix)
{
  const int i = blockIdx.x, h = blockIdx.y, dv = threadIdx.x;
  const int c = h*DH + dv;
  float accl = 0.f, accm = 0.f, accs = 0.f;
  {
    const int js = (i >= 62) ? 0 : (62 - i);
    for (int j=js;j<63;j++){
      const int ii = i - 62 + j;
      accl += v[(size_t)ii*DMOD + c] * ftl[(size_t)j*DMOD + c];
    }
  }
  {
    const int js = (i >= 14) ? 0 : (14 - i);
    for (int j=js;j<15;j++){
      const int ii = i - 14 + j;
      accm += v[(size_t)ii*DMOD + c] * ftm[(size_t)j*DMOD + c];
    }
  }
  {
    const int js = (i >= 2) ? 0 : (2 - i);
    for (int j=js;j<3;j++){
      const int ii = i - 2 + j;
      accs += v[(size_t)ii*DMOD + c] * fts[(size_t)j*DMOD + c];
    }
  }
  const float* pr = probs + ((size_t)i*NH + h)*5;
  const float p0 = pr[0], p1 = pr[1], p2 = pr[2], p3 = pr[3], p4 = pr[4];
  const float dvv = dout[(size_t)i*DMOD + c];
  const float vv  = v[(size_t)i*DMOD + c];
  float mix = p0*accs + p1*accm + p2*accl + p3*dvv + p4*vv;
  // RMSNorm over the 256 lanes of this head
  float ss = mix*mix;
  #pragma unroll
  for (int m=1;m<64;m<<=1) ss += __shfl_xor(ss, m, 64);
  __shared__ float pr4[4];
  if ((threadIdx.x & 63) == 0) pr4[threadIdx.x >> 6] = ss;
  __syncthreads();
  const float tot = pr4[0]+pr4[1]+pr4[2]+pr4[3];
  const float o = mix * rsqrtf(tot*(1.f/256.f) + 1e-5f) * normw[dv];
  omix[(size_t)i*DMOD + c] = o;
}

// ---------------- launch ----------------
extern "C" void kernel_launch(void* const* d_in, const int* in_sizes, int n_in,
                              void* d_out, int out_size, void* d_ws, size_t ws_size,
                              hipStream_t stream)
{
  const float* hidden = (const float*)d_in[0];
  const float* Wq     = (const float*)d_in[1];
  const float* Wk     = (const float*)d_in[2];
  const float* Wv     = (const float*)d_in[3];
  const float* Wb     = (const float*)d_in[4];
  const float* convq  = (const float*)d_in[5];
  const float* convk  = (const float*)d_in[6];
  const float* convv  = (const float*)d_in[7];
  const float* firs   = (const float*)d_in[8];
  const float* firm   = (const float*)d_in[9];
  const float* firl   = (const float*)d_in[10];
  const float* gatew  = (const float*)d_in[11];
  const float* gateb  = (const float*)d_in[12];
  const float* logtemp= (const float*)d_in[13];
  const float* epsp   = (const float*)d_in[14];
  const float* normw  = (const float*)d_in[15];
  const float* Wo     = (const float*)d_in[16];
  float* out = (float*)d_out;

  char* W = (char*)d_ws;
  const size_t MB = (size_t)1 << 20;
  float* tmp   = (float*)(W + 0*MB);    // 8MB: pre-conv GEMM out, later u-buffer
  float* qb    = (float*)(W + 8*MB);
  float* kb    = (float*)(W + 16*MB);
  float* vb    = (float*)(W + 24*MB);
  float* wb    = (float*)(W + 32*MB);
  float* dob   = (float*)(W + 40*MB);
  float* omix  = (float*)(W + 48*MB);
  float* attnb = (float*)(W + 56*MB);               // 1MB
  float* betab = (float*)(W + 57*MB);               // 32KB
  float* probs = (float*)(W + 57*MB + 262144);      // 160KB
  float* ftl   = (float*)(W + 58*MB);               // 252KB
  float* ftm   = (float*)(W + 58*MB + 300*1024);    // 60KB
  float* fts   = (float*)(W + 58*MB + 380*1024);    // 12KB

  prep_fir<<<324, 256, 0, stream>>>(firs, firm, firl, fts, ftm, ftl);

  gemm_f32<<<dim3(32,16), 256, 0, stream>>>(hidden, Wq, tmp, LSEQ, DMOD, DMOD);
  conv_silu<<<8192, 256, 0, stream>>>(tmp, convq, qb);
  gemm_f32<<<dim3(32,16), 256, 0, stream>>>(hidden, Wk, tmp, LSEQ, DMOD, DMOD);
  conv_silu<<<8192, 256, 0, stream>>>(tmp, convk, kb);
  gemm_f32<<<dim3(32,16), 256, 0, stream>>>(hidden, Wv, tmp, LSEQ, DMOD, DMOD);
  conv_silu<<<8192, 256, 0, stream>>>(tmp, convv, vb);

  beta_gate<<<2048, 256, 0, stream>>>(hidden, Wb, gatew, gateb, logtemp, epsp, betab, probs);

  delta_pre<<<dim3(64,4), 256, 0, stream>>>(qb, kb, vb, betab, wb, tmp, attnb);
  delta_scan<<<dim3(8,4), 512, 0, stream>>>(qb, kb, wb, tmp, attnb, dob);

  fir_mix<<<dim3(2048,4), 256, 0, stream>>>(vb, dob, probs, ftl, ftm, fts, normw, omix);

  gemm_f32<<<dim3(32,16), 256, 0, stream>>>(omix, Wo, out, LSEQ, DMOD, DMOD);
}

// Round 2
// 559.142 us; speedup vs baseline: 2.3065x; 2.3065x over previous
//
#include <hip/hip_runtime.h>

#define LSEQ 2048
#define DMOD 1024
#define NH   4
#define DH   256
#define NCH  64
#define CPAD 260

typedef unsigned short u16;
typedef short bf16x8 __attribute__((ext_vector_type(8)));
typedef float f32x4  __attribute__((ext_vector_type(4)));

#define MFMA16(a,b,c) __builtin_amdgcn_mfma_f32_16x16x32_bf16((a),(b),(c),0,0,0)

__device__ __forceinline__ float sigf(float x){ return 1.0f/(1.0f + expf(-x)); }

__device__ __forceinline__ u16 f2bf(float f){
  unsigned u = __float_as_uint(f);
  return (u16)((u + 0x7FFFu + ((u>>16)&1u)) >> 16);
}
__device__ __forceinline__ unsigned pk2(float a, float b){
  return (unsigned)f2bf(a) | ((unsigned)f2bf(b) << 16);
}

__device__ __forceinline__ void stage16(const void* g, void* l){
  __builtin_amdgcn_global_load_lds((const __attribute__((address_space(1))) unsigned*)g,
                                   (__attribute__((address_space(3))) unsigned*)l, 16, 0, 0);
}

// ---------------- fp32 -> bf16 convert ----------------
__global__ __launch_bounds__(256) void cvt_bf16(const float* __restrict__ src,
                                                u16* __restrict__ dst, int n4){
  int i = blockIdx.x*256 + threadIdx.x;
  if (i < n4){
    float4 v = ((const float4*)src)[i];
    ((uint2*)dst)[i] = make_uint2(pk2(v.x,v.y), pk2(v.z,v.w));
  }
}

// ---------------- bf16 MFMA GEMM: C[M][N]f32 = A[M][K] @ B[N][K]^T ----------------
// 128x128 tile, BK=32, 256 threads (4 waves, 2x2), global_load_lds staging, dbuf.
__global__ __launch_bounds__(256) void gemm_bf16(
    const u16* __restrict__ A, const u16* __restrict__ B,
    float* __restrict__ C, int M, int N, int K)
{
  __shared__ __align__(16) u16 Asl[2][128][32];
  __shared__ __align__(16) u16 Bsl[2][128][32];
  const int i0 = blockIdx.x*128, j0 = blockIdx.y*128;
  const int t = threadIdx.x, lane = t & 63, wv = t >> 6;
  const int wm = wv >> 1, wn = wv & 1;
  const int li = lane & 15, g = lane >> 4;
  const int lr = lane >> 2, lc = lane & 3;
  f32x4 acc[4][4] = {};

  auto stageAB = [&](int buf, int kt){
    const int k0 = kt*32;
    #pragma unroll
    for (int c2=0;c2<2;c2++){
      const int row = wv*32 + c2*16 + lr;
      stage16(A + (size_t)(i0+row)*K + k0 + lc*8, &Asl[buf][wv*32 + c2*16][0]);
      stage16(B + (size_t)(j0+row)*K + k0 + lc*8, &Bsl[buf][wv*32 + c2*16][0]);
    }
  };

  int buf = 0;
  const int nk = K/32;
  stageAB(0, 0);
  for (int kt=0; kt<nk; kt++){
    __syncthreads();
    if (kt+1 < nk) stageAB(buf^1, kt+1);
    bf16x8 af[4], bf[4];
    #pragma unroll
    for (int mt=0;mt<4;mt++) af[mt] = *(const bf16x8*)&Asl[buf][wm*64+mt*16+li][g*8];
    #pragma unroll
    for (int nt=0;nt<4;nt++) bf[nt] = *(const bf16x8*)&Bsl[buf][wn*64+nt*16+li][g*8];
    #pragma unroll
    for (int mt=0;mt<4;mt++)
      #pragma unroll
      for (int nt=0;nt<4;nt++)
        acc[mt][nt] = MFMA16(af[mt], bf[nt], acc[mt][nt]);
    buf ^= 1;
  }
  #pragma unroll
  for (int mt=0;mt<4;mt++){
    #pragma unroll
    for (int nt=0;nt<4;nt++){
      #pragma unroll
      for (int r=0;r<4;r++){
        const int row = i0 + wm*64 + mt*16 + g*4 + r;
        const int col = j0 + wn*64 + nt*16 + li;
        C[(size_t)row*N + col] = acc[mt][nt][r];
      }
    }
  }
}

// ---------------- depthwise causal conv (K=4) + silu ----------------
__global__ __launch_bounds__(256) void conv_silu(
    const float* __restrict__ x, const float* __restrict__ w, float* __restrict__ y)
{
  const int idx = blockIdx.x*256 + threadIdx.x;
  const int c = idx & (DMOD-1);
  const int i = idx >> 10;
  float4 wc = *(const float4*)(w + (size_t)c*4);
  float acc = wc.w * x[idx];
  if (i >= 1) acc += wc.z * x[idx -   DMOD];
  if (i >= 2) acc += wc.y * x[idx - 2*DMOD];
  if (i >= 3) acc += wc.x * x[idx - 3*DMOD];
  y[idx] = acc * sigf(acc);
}

// ---------------- beta (sigmoid) + 5-way gate probs per row ----------------
__global__ __launch_bounds__(256) void beta_gate(
    const float* __restrict__ hidden, const float* __restrict__ Wb,
    const float* __restrict__ gw, const float* __restrict__ gb,
    const float* __restrict__ logtemp, const float* __restrict__ epsp,
    float* __restrict__ betab, float* __restrict__ probs)
{
  const int i = blockIdx.x, t = threadIdx.x;
  float4 h4 = *(const float4*)(hidden + (size_t)i*DMOD + t*4);
  float part[24];
  #pragma unroll
  for (int o=0;o<24;o++){
    const float* wr = (o<4) ? (Wb + (size_t)o*DMOD) : (gw + (size_t)(o-4)*DMOD);
    float4 w4 = *(const float4*)(wr + t*4);
    part[o] = h4.x*w4.x + h4.y*w4.y + h4.z*w4.z + h4.w*w4.w;
  }
  __shared__ float red[24][4];
  __shared__ float fin[24];
  const int lane = t & 63, wv = t >> 6;
  #pragma unroll
  for (int o=0;o<24;o++){
    float vv = part[o];
    #pragma unroll
    for (int m=1;m<64;m<<=1) vv += __shfl_xor(vv, m, 64);
    if (lane == 0) red[o][wv] = vv;
  }
  __syncthreads();
  if (t < 24) fin[t] = red[t][0]+red[t][1]+red[t][2]+red[t][3];
  __syncthreads();
  if (t < NH){
    const int hh = t;
    betab[(size_t)i*NH + hh] = sigf(fin[hh]);
    float temp = expf(logtemp[hh]);
    float lg[5], mx = -1e30f;
    #pragma unroll
    for (int p=0;p<5;p++){ lg[p] = (fin[4+hh*5+p] + gb[hh*5+p]) / temp; mx = fmaxf(mx, lg[p]); }
    float ex[5], s = 0.f;
    #pragma unroll
    for (int p=0;p<5;p++){ ex[p] = expf(lg[p]-mx); s += ex[p]; }
    float eps = fminf(fmaxf(epsp[hh], 0.f), 0.2f);
    #pragma unroll
    for (int p=0;p<5;p++) probs[((size_t)i*NH+hh)*5 + p] = (ex[p]/s)*(1.f-5.f*eps) + eps;
  }
}

// ---------------- delta precompute: per (chunk, head) ----------------
// emits bf16 MFMA-ready operands: q (row-major), -w (row-major), kT [dk][c], attn [c][c'],
// and u (fp32).
__global__ __launch_bounds__(256) void delta_pre(
    const float* __restrict__ q, const float* __restrict__ k, const float* __restrict__ v,
    const float* __restrict__ beta,
    u16* __restrict__ qbg, u16* __restrict__ wng, u16* __restrict__ kTg,
    u16* __restrict__ atg, float* __restrict__ ubuf)
{
  const int n = blockIdx.x, h = blockIdx.y;
  const int t = threadIdx.x;
  __shared__ float q_s[32][CPAD], k_s[32][CPAD], v_s[32][CPAD];
  __shared__ float T_s[32][32], Tb_s[32][32], M_s[32][32];
  __shared__ float rr[2][32][8];
  __shared__ float scl[2][32];
  __shared__ float bet_s[32];

  const int row = t >> 3, cq = t & 7;
  const size_t gb = (size_t)(n*32+row)*DMOD + h*DH + cq*32;
  const size_t cb = (size_t)(h*NCH+n)*32*256;   // bf16 chunk base (elements)
  float psq = 0.f, psk = 0.f;
  #pragma unroll
  for (int x=0;x<8;x++){
    float4 qa = *(const float4*)(q + gb + x*4);
    float4 ka = *(const float4*)(k + gb + x*4);
    float4 va = *(const float4*)(v + gb + x*4);
    *(float4*)&q_s[row][cq*32+x*4] = qa;
    *(float4*)&k_s[row][cq*32+x*4] = ka;
    *(float4*)&v_s[row][cq*32+x*4] = va;
    psq += qa.x*qa.x+qa.y*qa.y+qa.z*qa.z+qa.w*qa.w;
    psk += ka.x*ka.x+ka.y*ka.y+ka.z*ka.z+ka.w*ka.w;
  }
  rr[0][row][cq] = psq; rr[1][row][cq] = psk;
  if (t < 32) bet_s[t] = beta[(size_t)(n*32+t)*NH + h];
  __syncthreads();
  if (t < 64){
    const int wh = t >> 5, r = t & 31;
    float s = 1e-6f;
    #pragma unroll
    for (int x=0;x<8;x++) s += rr[wh][r][x];
    scl[wh][r] = rsqrtf(s);
  }
  __syncthreads();
  {
    const float sq = scl[0][row], sk2 = scl[1][row];
    #pragma unroll
    for (int x=0;x<8;x++){
      float4 qa = *(float4*)&q_s[row][cq*32+x*4];
      qa.x*=sq; qa.y*=sq; qa.z*=sq; qa.w*=sq;
      *(float4*)&q_s[row][cq*32+x*4] = qa;
      *(uint2*)&qbg[cb + (size_t)row*256 + cq*32 + x*4] = make_uint2(pk2(qa.x,qa.y), pk2(qa.z,qa.w));
      float4 ka = *(float4*)&k_s[row][cq*32+x*4];
      ka.x*=sk2; ka.y*=sk2; ka.z*=sk2; ka.w*=sk2;
      *(float4*)&k_s[row][cq*32+x*4] = ka;
    }
  }
  __syncthreads();
  // kT bf16 [dk=256][c=32]: thread t owns dk-row t
  {
    unsigned* kp = (unsigned*)(kTg + ((size_t)(h*NCH+n)*256 + t)*32);
    #pragma unroll
    for (int c2=0;c2<16;c2++)
      kp[c2] = pk2(k_s[2*c2][t], k_s[2*c2+1][t]);
  }
  // M matrix
  {
    const int c = t >> 3, m0 = (t & 7)*4;
    float d0=0.f,d1=0.f,d2=0.f,d3=0.f;
    for (int kk=0;kk<DH;kk+=4){
      float4 a  = *(const float4*)&k_s[c][kk];
      float4 b0 = *(const float4*)&k_s[m0+0][kk];
      float4 b1 = *(const float4*)&k_s[m0+1][kk];
      float4 b2 = *(const float4*)&k_s[m0+2][kk];
      float4 b3 = *(const float4*)&k_s[m0+3][kk];
      d0 += a.x*b0.x + a.y*b0.y + a.z*b0.z + a.w*b0.w;
      d1 += a.x*b1.x + a.y*b1.y + a.z*b1.z + a.w*b1.w;
      d2 += a.x*b2.x + a.y*b2.y + a.z*b2.z + a.w*b2.w;
      d3 += a.x*b3.x + a.y*b3.y + a.z*b3.z + a.w*b3.w;
    }
    const float bc = bet_s[c];
    M_s[c][m0+0] = (m0+0 < c) ? bc*d0 : ((m0+0==c)?1.f:0.f);
    M_s[c][m0+1] = (m0+1 < c) ? bc*d1 : ((m0+1==c)?1.f:0.f);
    M_s[c][m0+2] = (m0+2 < c) ? bc*d2 : ((m0+2==c)?1.f:0.f);
    M_s[c][m0+3] = (m0+3 < c) ? bc*d3 : ((m0+3==c)?1.f:0.f);
  }
  __syncthreads();
  // T = M^-1 forward substitution, column j per lane
  if (t < 32){
    const int j = t;
    for (int c=0;c<32;c++){
      float s = (c==j) ? 1.f : 0.f;
      for (int m=0;m<c;m++) s -= M_s[c][m]*T_s[m][j];
      T_s[c][j] = s;
    }
  }
  __syncthreads();
  {
    const int c = t >> 3, m0 = (t & 7)*4;
    #pragma unroll
    for (int x=0;x<4;x++) Tb_s[c][m0+x] = T_s[c][m0+x]*bet_s[m0+x];
  }
  __syncthreads();
  // w = Tb @ k_s (emit -w bf16); u = Tb @ v_s (fp32)
  {
    const int colb = (t & 7)*4;
    float4 aw[8] = {};
    float4 au[8] = {};
    for (int m=0;m<32;m++){
      const float tb = Tb_s[row][m];
      #pragma unroll
      for (int y=0;y<8;y++){
        float4 kv = *(const float4*)&k_s[m][colb + y*32];
        float4 vv = *(const float4*)&v_s[m][colb + y*32];
        aw[y].x += tb*kv.x; aw[y].y += tb*kv.y; aw[y].z += tb*kv.z; aw[y].w += tb*kv.w;
        au[y].x += tb*vv.x; au[y].y += tb*vv.y; au[y].z += tb*vv.z; au[y].w += tb*vv.w;
      }
    }
    const size_t ob = (size_t)(n*32+row)*DMOD + h*DH + colb;
    #pragma unroll
    for (int y=0;y<8;y++){
      *(uint2*)&wng[cb + (size_t)row*256 + colb + y*32] =
          make_uint2(pk2(-aw[y].x,-aw[y].y), pk2(-aw[y].z,-aw[y].w));
      *(float4*)(ubuf + ob + y*32) = au[y];
    }
  }
  // attn = tril(q k^T) bf16 [c][c']
  {
    const int c = t >> 3, m0 = (t & 7)*4;
    float d0=0.f,d1=0.f,d2=0.f,d3=0.f;
    for (int kk=0;kk<DH;kk+=4){
      float4 a  = *(const float4*)&q_s[c][kk];
      float4 b0 = *(const float4*)&k_s[m0+0][kk];
      float4 b1 = *(const float4*)&k_s[m0+1][kk];
      float4 b2 = *(const float4*)&k_s[m0+2][kk];
      float4 b3 = *(const float4*)&k_s[m0+3][kk];
      d0 += a.x*b0.x + a.y*b0.y + a.z*b0.z + a.w*b0.w;
      d1 += a.x*b1.x + a.y*b1.y + a.z*b1.z + a.w*b1.w;
      d2 += a.x*b2.x + a.y*b2.y + a.z*b2.z + a.w*b2.w;
      d3 += a.x*b3.x + a.y*b3.y + a.z*b3.z + a.w*b3.w;
    }
    d0 = (m0+0 <= c) ? d0 : 0.f;
    d1 = (m0+1 <= c) ? d1 : 0.f;
    d2 = (m0+2 <= c) ? d2 : 0.f;
    d3 = (m0+3 <= c) ? d3 : 0.f;
    *(uint2*)&atg[((size_t)(h*NCH+n)*32 + c)*32 + m0] =
        make_uint2(pk2(d0,d1), pk2(d2,d3));
  }
}

// ---------------- fused delta scan: MFMA, S in regs, o fused ----------------
// grid (4 dv-quarters, 4 heads), 256 threads = 4 waves; wave owns dv-16 slice.
__global__ __launch_bounds__(256) void delta_scan_fused(
    const u16* __restrict__ qbg, const u16* __restrict__ wng,
    const u16* __restrict__ kTg, const u16* __restrict__ atg,
    const float* __restrict__ ubuf, float* __restrict__ dob)
{
  const int qd = blockIdx.x, h = blockIdx.y;
  const int t = threadIdx.x, lane = t & 63, wv = t >> 6;
  __shared__ __align__(16) u16 w_l[32][264];
  __shared__ __align__(16) u16 q_l[32][264];
  __shared__ __align__(16) u16 kT_l[256][40];
  __shared__ __align__(16) u16 at_l[32][40];
  __shared__ __align__(16) float u_l[32][68];
  __shared__ __align__(16) u16 ST[4][16][264];
  __shared__ __align__(16) u16 uaT[4][16][40];

  f32x4 S[16];
  #pragma unroll
  for (int i=0;i<16;i++) S[i] = (f32x4){0.f,0.f,0.f,0.f};
  for (int i=lane; i<16*264; i+=64) (&ST[wv][0][0])[i] = 0;

  const int g = lane >> 4, li = lane & 15;
  const int srow = t >> 3, scg = t & 7;

  for (int n=0;n<NCH;n++){
    __syncthreads();
    // ---- stage ----
    {
      const size_t cbs = (size_t)(h*NCH+n)*32*256;
      const u16* wsrc = wng + cbs + (size_t)srow*256 + scg*32;
      const u16* qsrc = qbg + cbs + (size_t)srow*256 + scg*32;
      #pragma unroll
      for (int i=0;i<4;i++){
        *(uint4*)&w_l[srow][scg*32 + i*8] = *(const uint4*)(wsrc + i*8);
        *(uint4*)&q_l[srow][scg*32 + i*8] = *(const uint4*)(qsrc + i*8);
      }
      const u16* ksrc = kTg + (size_t)(h*NCH+n)*256*32 + (size_t)t*32;
      #pragma unroll
      for (int i=0;i<4;i++)
        *(uint4*)&kT_l[t][i*8] = *(const uint4*)(ksrc + i*8);
      const float* usrc = ubuf + (size_t)(n*32 + srow)*DMOD + h*DH + qd*64 + scg*8;
      *(float4*)&u_l[srow][scg*8]   = *(const float4*)(usrc);
      *(float4*)&u_l[srow][scg*8+4] = *(const float4*)(usrc+4);
      if (t < 128){
        const u16* asrc = atg + (size_t)(h*NCH+n)*32*32 + (t>>2)*32 + (t&3)*8;
        *(uint4*)&at_l[t>>2][(t&3)*8] = *(const uint4*)(asrc);
      }
    }
    __syncthreads();

    // ---- ua = u - w @ S_n  (A = -w, B = ST) ----
    bf16x8 Bs[8];
    #pragma unroll
    for (int kb=0;kb<8;kb++)
      Bs[kb] = *(const bf16x8*)&ST[wv][li][kb*32 + g*8];
    f32x4 ua0, ua1;
    #pragma unroll
    for (int r=0;r<4;r++){
      ua0[r] = u_l[g*4+r][wv*16+li];
      ua1[r] = u_l[16+g*4+r][wv*16+li];
    }
    #pragma unroll
    for (int kb=0;kb<8;kb++){
      bf16x8 a0 = *(const bf16x8*)&w_l[li   ][kb*32 + g*8];
      bf16x8 a1 = *(const bf16x8*)&w_l[16+li][kb*32 + g*8];
      ua0 = MFMA16(a0, Bs[kb], ua0);
      ua1 = MFMA16(a1, Bs[kb], ua1);
    }
    // write uaT (bf16, wave-private)
    *(unsigned*)&uaT[wv][li][g*4]        = pk2(ua0[0], ua0[1]);
    *(unsigned*)&uaT[wv][li][g*4 + 2]    = pk2(ua0[2], ua0[3]);
    *(unsigned*)&uaT[wv][li][16 + g*4]   = pk2(ua1[0], ua1[1]);
    *(unsigned*)&uaT[wv][li][16 + g*4+2] = pk2(ua1[2], ua1[3]);

    // ---- S += kT @ ua ----
    bf16x8 bu = *(const bf16x8*)&uaT[wv][li][g*8];
    #pragma unroll
    for (int mt=0;mt<16;mt++){
      bf16x8 a = *(const bf16x8*)&kT_l[mt*16 + li][g*8];
      S[mt] = MFMA16(a, bu, S[mt]);
    }

    // ---- o = q @ S_n + attn @ ua ----
    f32x4 o0 = (f32x4){0.f,0.f,0.f,0.f}, o1 = (f32x4){0.f,0.f,0.f,0.f};
    #pragma unroll
    for (int kb=0;kb<8;kb++){
      bf16x8 a0 = *(const bf16x8*)&q_l[li   ][kb*32 + g*8];
      bf16x8 a1 = *(const bf16x8*)&q_l[16+li][kb*32 + g*8];
      o0 = MFMA16(a0, Bs[kb], o0);
      o1 = MFMA16(a1, Bs[kb], o1);
    }
    {
      bf16x8 a0 = *(const bf16x8*)&at_l[li   ][g*8];
      bf16x8 a1 = *(const bf16x8*)&at_l[16+li][g*8];
      o0 = MFMA16(a0, bu, o0);
      o1 = MFMA16(a1, bu, o1);
    }

    // ---- refresh ST shadow from S regs (S_{n+1}) ----
    #pragma unroll
    for (int mt=0;mt<16;mt++){
      *(unsigned*)&ST[wv][li][mt*16 + g*4]     = pk2(S[mt][0], S[mt][1]);
      *(unsigned*)&ST[wv][li][mt*16 + g*4 + 2] = pk2(S[mt][2], S[mt][3]);
    }

    // ---- store o ----
    const size_t ob = (size_t)(n*32)*DMOD + h*DH + qd*64 + wv*16 + li;
    #pragma unroll
    for (int r=0;r<4;r++){
      dob[ob + (size_t)(g*4+r)*DMOD]    = o0[r];
      dob[ob + (size_t)(16+g*4+r)*DMOD] = o1[r];
    }
  }
}

// ---------------- transpose FIR filters to [j][c] ----------------
__global__ void prep_fir(const float* __restrict__ fs, const float* __restrict__ fm,
                         const float* __restrict__ fl, float* __restrict__ fts,
                         float* __restrict__ ftm, float* __restrict__ ftl)
{
  const int idx = blockIdx.x*256 + threadIdx.x;
  if (idx < 63*1024){
    const int j = idx >> 10, c = idx & 1023;
    ftl[idx] = fl[(size_t)c*63 + j];
  } else if (idx < 78*1024){
    const int r = idx - 63*1024;
    const int j = r >> 10, c = r & 1023;
    ftm[r] = fm[(size_t)c*15 + j];
  } else {
    const int r = idx - 78*1024;
    const int j = r >> 10, c = r & 1023;
    fts[r] = fs[(size_t)c*3 + j];
  }
}

// ---------------- FIR convs + gated mix + per-head RMSNorm (bf16 out) ----------------
__global__ __launch_bounds__(256) void fir_mix(
    const float* __restrict__ v, const float* __restrict__ dout,
    const float* __restrict__ probs, const float* __restrict__ ftl,
    const float* __restrict__ ftm, const float* __restrict__ fts,
    const float* __restrict__ normw, u16* __restrict__ omixb)
{
  const int i = blockIdx.x, h = blockIdx.y, dv = threadIdx.x;
  const int c = h*DH + dv;
  float accl = 0.f, accm = 0.f, accs = 0.f;
  {
    const int js = (i >= 62) ? 0 : (62 - i);
    for (int j=js;j<63;j++)
      accl += v[(size_t)(i-62+j)*DMOD + c] * ftl[(size_t)j*DMOD + c];
  }
  {
    const int js = (i >= 14) ? 0 : (14 - i);
    for (int j=js;j<15;j++)
      accm += v[(size_t)(i-14+j)*DMOD + c] * ftm[(size_t)j*DMOD + c];
  }
  {
    const int js = (i >= 2) ? 0 : (2 - i);
    for (int j=js;j<3;j++)
      accs += v[(size_t)(i-2+j)*DMOD + c] * fts[(size_t)j*DMOD + c];
  }
  const float* pr = probs + ((size_t)i*NH + h)*5;
  const float dvv = dout[(size_t)i*DMOD + c];
  const float vv  = v[(size_t)i*DMOD + c];
  float mix = pr[0]*accs + pr[1]*accm + pr[2]*accl + pr[3]*dvv + pr[4]*vv;
  float ss = mix*mix;
  #pragma unroll
  for (int m=1;m<64;m<<=1) ss += __shfl_xor(ss, m, 64);
  __shared__ float pr4[4];
  if ((threadIdx.x & 63) == 0) pr4[threadIdx.x >> 6] = ss;
  __syncthreads();
  const float tot = pr4[0]+pr4[1]+pr4[2]+pr4[3];
  const float o = mix * rsqrtf(tot*(1.f/256.f) + 1e-5f) * normw[dv];
  omixb[(size_t)i*DMOD + c] = f2bf(o);
}

// ---------------- launch ----------------
extern "C" void kernel_launch(void* const* d_in, const int* in_sizes, int n_in,
                              void* d_out, int out_size, void* d_ws, size_t ws_size,
                              hipStream_t stream)
{
  const float* hidden = (const float*)d_in[0];
  const float* Wq     = (const float*)d_in[1];
  const float* Wk     = (const float*)d_in[2];
  const float* Wv     = (const float*)d_in[3];
  const float* Wb     = (const float*)d_in[4];
  const float* convq  = (const float*)d_in[5];
  const float* convk  = (const float*)d_in[6];
  const float* convv  = (const float*)d_in[7];
  const float* firs   = (const float*)d_in[8];
  const float* firm   = (const float*)d_in[9];
  const float* firl   = (const float*)d_in[10];
  const float* gatew  = (const float*)d_in[11];
  const float* gateb  = (const float*)d_in[12];
  const float* logtemp= (const float*)d_in[13];
  const float* epsp   = (const float*)d_in[14];
  const float* normw  = (const float*)d_in[15];
  const float* Wo     = (const float*)d_in[16];
  float* out = (float*)d_out;

  char* W = (char*)d_ws;
  const size_t MB = (size_t)1 << 20;
  float* tmp   = (float*)(W + 0*MB);         // 8MB: pre-conv GEMM out; later u
  float* qb    = (float*)(W + 8*MB);         // 8MB; dob aliases after delta_pre
  float* dob   = (float*)(W + 8*MB);
  float* kb    = (float*)(W + 16*MB);        // 8MB; omixb aliases after delta_pre
  u16*   omixb = (u16*)  (W + 16*MB);
  float* vb    = (float*)(W + 24*MB);        // 8MB
  u16*   hidb  = (u16*)  (W + 32*MB);        // 4MB
  u16*   wqb   = (u16*)  (W + 36*MB);        // 2MB
  u16*   wkb   = (u16*)  (W + 38*MB);        // 2MB
  u16*   wvb   = (u16*)  (W + 40*MB);        // 2MB
  u16*   wob   = (u16*)  (W + 42*MB);        // 2MB
  u16*   qbg   = (u16*)  (W + 44*MB);        // 4MB
  u16*   wng   = (u16*)  (W + 48*MB);        // 4MB
  u16*   kTg   = (u16*)  (W + 52*MB);        // 4MB
  u16*   atg   = (u16*)  (W + 56*MB);        // 0.5MB
  float* betab = (float*)(W + 56*MB + 524288);            // 32KB
  float* probs = (float*)(W + 56*MB + 524288 + 32768);    // 160KB
  float* ftl   = (float*)(W + 57*MB);                     // 252KB
  float* ftm   = (float*)(W + 57*MB + 300*1024);          // 60KB
  float* fts   = (float*)(W + 57*MB + 380*1024);          // 12KB

  cvt_bf16<<<2048, 256, 0, stream>>>(hidden, hidb, 2048*1024/4);
  cvt_bf16<<<1024, 256, 0, stream>>>(Wq, wqb, 1024*1024/4);
  cvt_bf16<<<1024, 256, 0, stream>>>(Wk, wkb, 1024*1024/4);
  cvt_bf16<<<1024, 256, 0, stream>>>(Wv, wvb, 1024*1024/4);
  cvt_bf16<<<1024, 256, 0, stream>>>(Wo, wob, 1024*1024/4);
  prep_fir<<<324, 256, 0, stream>>>(firs, firm, firl, fts, ftm, ftl);

  gemm_bf16<<<dim3(16,8), 256, 0, stream>>>(hidb, wqb, tmp, LSEQ, DMOD, DMOD);
  conv_silu<<<8192, 256, 0, stream>>>(tmp, convq, qb);
  gemm_bf16<<<dim3(16,8), 256, 0, stream>>>(hidb, wkb, tmp, LSEQ, DMOD, DMOD);
  conv_silu<<<8192, 256, 0, stream>>>(tmp, convk, kb);
  gemm_bf16<<<dim3(16,8), 256, 0, stream>>>(hidb, wvb, tmp, LSEQ, DMOD, DMOD);
  conv_silu<<<8192, 256, 0, stream>>>(tmp, convv, vb);

  beta_gate<<<2048, 256, 0, stream>>>(hidden, Wb, gatew, gateb, logtemp, epsp, betab, probs);

  delta_pre<<<dim3(64,4), 256, 0, stream>>>(qb, kb, vb, betab, qbg, wng, kTg, atg, tmp);
  delta_scan_fused<<<dim3(4,4), 256, 0, stream>>>(qbg, wng, kTg, atg, tmp, dob);

  fir_mix<<<dim3(2048,4), 256, 0, stream>>>(vb, dob, probs, ftl, ftm, fts, normw, omixb);

  gemm_bf16<<<dim3(16,8), 256, 0, stream>>>(omixb, wob, out, LSEQ, DMOD, DMOD);
}

// Round 3
// 534.836 us; speedup vs baseline: 2.4114x; 1.0454x over previous
//
#include <hip/hip_runtime.h>

#define LSEQ 2048
#define DMOD 1024
#define NH   4
#define DH   256
#define NCH  64
#define CPAD 260

typedef unsigned short u16;
typedef short bf16x8 __attribute__((ext_vector_type(8)));
typedef float f32x4  __attribute__((ext_vector_type(4)));

#define MFMA16(a,b,c) __builtin_amdgcn_mfma_f32_16x16x32_bf16((a),(b),(c),0,0,0)

__device__ __forceinline__ float sigf(float x){ return 1.0f/(1.0f + expf(-x)); }

__device__ __forceinline__ u16 f2bf(float f){
  unsigned u = __float_as_uint(f);
  return (u16)((u + 0x7FFFu + ((u>>16)&1u)) >> 16);
}
__device__ __forceinline__ unsigned pk2(float a, float b){
  return (unsigned)f2bf(a) | ((unsigned)f2bf(b) << 16);
}

__device__ __forceinline__ void stage16(const void* g, void* l){
  __builtin_amdgcn_global_load_lds((const __attribute__((address_space(1))) unsigned*)g,
                                   (__attribute__((address_space(3))) unsigned*)l, 16, 0, 0);
}

// ---------------- fp32 -> bf16 convert ----------------
__global__ __launch_bounds__(256) void cvt_bf16(const float* __restrict__ src,
                                                u16* __restrict__ dst, int n4){
  int i = blockIdx.x*256 + threadIdx.x;
  if (i < n4){
    float4 v = ((const float4*)src)[i];
    ((uint2*)dst)[i] = make_uint2(pk2(v.x,v.y), pk2(v.z,v.w));
  }
}

// ---------------- bf16 MFMA GEMM: C[M][N]f32 = A[M][K] @ B[N][K]^T ----------------
__global__ __launch_bounds__(256) void gemm_bf16(
    const u16* __restrict__ A, const u16* __restrict__ B,
    float* __restrict__ C, int M, int N, int K)
{
  __shared__ __align__(16) u16 Asl[2][128][32];
  __shared__ __align__(16) u16 Bsl[2][128][32];
  const int i0 = blockIdx.x*128, j0 = blockIdx.y*128;
  const int t = threadIdx.x, lane = t & 63, wv = t >> 6;
  const int wm = wv >> 1, wn = wv & 1;
  const int li = lane & 15, g = lane >> 4;
  const int lr = lane >> 2, lc = lane & 3;
  f32x4 acc[4][4] = {};

  auto stageAB = [&](int buf, int kt){
    const int k0 = kt*32;
    #pragma unroll
    for (int c2=0;c2<2;c2++){
      const int row = wv*32 + c2*16 + lr;
      stage16(A + (size_t)(i0+row)*K + k0 + lc*8, &Asl[buf][wv*32 + c2*16][0]);
      stage16(B + (size_t)(j0+row)*K + k0 + lc*8, &Bsl[buf][wv*32 + c2*16][0]);
    }
  };

  int buf = 0;
  const int nk = K/32;
  stageAB(0, 0);
  for (int kt=0; kt<nk; kt++){
    __syncthreads();
    if (kt+1 < nk) stageAB(buf^1, kt+1);
    bf16x8 af[4], bf[4];
    #pragma unroll
    for (int mt=0;mt<4;mt++) af[mt] = *(const bf16x8*)&Asl[buf][wm*64+mt*16+li][g*8];
    #pragma unroll
    for (int nt=0;nt<4;nt++) bf[nt] = *(const bf16x8*)&Bsl[buf][wn*64+nt*16+li][g*8];
    #pragma unroll
    for (int mt=0;mt<4;mt++)
      #pragma unroll
      for (int nt=0;nt<4;nt++)
        acc[mt][nt] = MFMA16(af[mt], bf[nt], acc[mt][nt]);
    buf ^= 1;
  }
  #pragma unroll
  for (int mt=0;mt<4;mt++){
    #pragma unroll
    for (int nt=0;nt<4;nt++){
      #pragma unroll
      for (int r=0;r<4;r++){
        const int row = i0 + wm*64 + mt*16 + g*4 + r;
        const int col = j0 + wn*64 + nt*16 + li;
        C[(size_t)row*N + col] = acc[mt][nt][r];
      }
    }
  }
}

// ---------------- depthwise causal conv (K=4) + silu ----------------
__global__ __launch_bounds__(256) void conv_silu(
    const float* __restrict__ x, const float* __restrict__ w, float* __restrict__ y)
{
  const int idx = blockIdx.x*256 + threadIdx.x;
  const int c = idx & (DMOD-1);
  const int i = idx >> 10;
  float4 wc = *(const float4*)(w + (size_t)c*4);
  float acc = wc.w * x[idx];
  if (i >= 1) acc += wc.z * x[idx -   DMOD];
  if (i >= 2) acc += wc.y * x[idx - 2*DMOD];
  if (i >= 3) acc += wc.x * x[idx - 3*DMOD];
  y[idx] = acc * sigf(acc);
}

// ---------------- beta (sigmoid) + 5-way gate probs per row ----------------
__global__ __launch_bounds__(256) void beta_gate(
    const float* __restrict__ hidden, const float* __restrict__ Wb,
    const float* __restrict__ gw, const float* __restrict__ gb,
    const float* __restrict__ logtemp, const float* __restrict__ epsp,
    float* __restrict__ betab, float* __restrict__ probs)
{
  const int i = blockIdx.x, t = threadIdx.x;
  float4 h4 = *(const float4*)(hidden + (size_t)i*DMOD + t*4);
  float part[24];
  #pragma unroll
  for (int o=0;o<24;o++){
    const float* wr = (o<4) ? (Wb + (size_t)o*DMOD) : (gw + (size_t)(o-4)*DMOD);
    float4 w4 = *(const float4*)(wr + t*4);
    part[o] = h4.x*w4.x + h4.y*w4.y + h4.z*w4.z + h4.w*w4.w;
  }
  __shared__ float red[24][4];
  __shared__ float fin[24];
  const int lane = t & 63, wv = t >> 6;
  #pragma unroll
  for (int o=0;o<24;o++){
    float vv = part[o];
    #pragma unroll
    for (int m=1;m<64;m<<=1) vv += __shfl_xor(vv, m, 64);
    if (lane == 0) red[o][wv] = vv;
  }
  __syncthreads();
  if (t < 24) fin[t] = red[t][0]+red[t][1]+red[t][2]+red[t][3];
  __syncthreads();
  if (t < NH){
    const int hh = t;
    betab[(size_t)i*NH + hh] = sigf(fin[hh]);
    float temp = expf(logtemp[hh]);
    float lg[5], mx = -1e30f;
    #pragma unroll
    for (int p=0;p<5;p++){ lg[p] = (fin[4+hh*5+p] + gb[hh*5+p]) / temp; mx = fmaxf(mx, lg[p]); }
    float ex[5], s = 0.f;
    #pragma unroll
    for (int p=0;p<5;p++){ ex[p] = expf(lg[p]-mx); s += ex[p]; }
    float eps = fminf(fmaxf(epsp[hh], 0.f), 0.2f);
    #pragma unroll
    for (int p=0;p<5;p++) probs[((size_t)i*NH+hh)*5 + p] = (ex[p]/s)*(1.f-5.f*eps) + eps;
  }
}

// ---------------- delta precompute: per (chunk, head) ----------------
// emits bf16 MFMA-ready operands: q,-w row-major XOR-SWIZZLED (idx ^= (row&7)<<3),
// kT [dk][c], attn [c][c'], u fp32.
__global__ __launch_bounds__(256) void delta_pre(
    const float* __restrict__ q, const float* __restrict__ k, const float* __restrict__ v,
    const float* __restrict__ beta,
    u16* __restrict__ qbg, u16* __restrict__ wng, u16* __restrict__ kTg,
    u16* __restrict__ atg, float* __restrict__ ubuf)
{
  const int n = blockIdx.x, h = blockIdx.y;
  const int t = threadIdx.x;
  __shared__ float q_s[32][CPAD], k_s[32][CPAD], v_s[32][CPAD];
  __shared__ float T_s[32][32], Tb_s[32][32], M_s[32][32];
  __shared__ float rr[2][32][8];
  __shared__ float scl[2][32];
  __shared__ float bet_s[32];

  const int row = t >> 3, cq = t & 7;
  const size_t gb = (size_t)(n*32+row)*DMOD + h*DH + cq*32;
  const size_t cb = (size_t)(h*NCH+n)*32*256;
  const int sw = (row & 7) << 3;               // global-side swizzle for q/w
  float psq = 0.f, psk = 0.f;
  #pragma unroll
  for (int x=0;x<8;x++){
    float4 qa = *(const float4*)(q + gb + x*4);
    float4 ka = *(const float4*)(k + gb + x*4);
    float4 va = *(const float4*)(v + gb + x*4);
    *(float4*)&q_s[row][cq*32+x*4] = qa;
    *(float4*)&k_s[row][cq*32+x*4] = ka;
    *(float4*)&v_s[row][cq*32+x*4] = va;
    psq += qa.x*qa.x+qa.y*qa.y+qa.z*qa.z+qa.w*qa.w;
    psk += ka.x*ka.x+ka.y*ka.y+ka.z*ka.z+ka.w*ka.w;
  }
  rr[0][row][cq] = psq; rr[1][row][cq] = psk;
  if (t < 32) bet_s[t] = beta[(size_t)(n*32+t)*NH + h];
  __syncthreads();
  if (t < 64){
    const int wh = t >> 5, r = t & 31;
    float s = 1e-6f;
    #pragma unroll
    for (int x=0;x<8;x++) s += rr[wh][r][x];
    scl[wh][r] = rsqrtf(s);
  }
  __syncthreads();
  {
    const float sq = scl[0][row], sk2 = scl[1][row];
    #pragma unroll
    for (int x=0;x<8;x++){
      float4 qa = *(float4*)&q_s[row][cq*32+x*4];
      qa.x*=sq; qa.y*=sq; qa.z*=sq; qa.w*=sq;
      *(float4*)&q_s[row][cq*32+x*4] = qa;
      *(uint2*)&qbg[cb + (size_t)row*256 + ((cq*32 + x*4) ^ sw)] =
          make_uint2(pk2(qa.x,qa.y), pk2(qa.z,qa.w));
      float4 ka = *(float4*)&k_s[row][cq*32+x*4];
      ka.x*=sk2; ka.y*=sk2; ka.z*=sk2; ka.w*=sk2;
      *(float4*)&k_s[row][cq*32+x*4] = ka;
    }
  }
  __syncthreads();
  // kT bf16 [dk=256][c=32]
  {
    unsigned* kp = (unsigned*)(kTg + ((size_t)(h*NCH+n)*256 + t)*32);
    #pragma unroll
    for (int c2=0;c2<16;c2++)
      kp[c2] = pk2(k_s[2*c2][t], k_s[2*c2+1][t]);
  }
  // M matrix
  {
    const int c = t >> 3, m0 = (t & 7)*4;
    float d0=0.f,d1=0.f,d2=0.f,d3=0.f;
    for (int kk=0;kk<DH;kk+=4){
      float4 a  = *(const float4*)&k_s[c][kk];
      float4 b0 = *(const float4*)&k_s[m0+0][kk];
      float4 b1 = *(const float4*)&k_s[m0+1][kk];
      float4 b2 = *(const float4*)&k_s[m0+2][kk];
      float4 b3 = *(const float4*)&k_s[m0+3][kk];
      d0 += a.x*b0.x + a.y*b0.y + a.z*b0.z + a.w*b0.w;
      d1 += a.x*b1.x + a.y*b1.y + a.z*b1.z + a.w*b1.w;
      d2 += a.x*b2.x + a.y*b2.y + a.z*b2.z + a.w*b2.w;
      d3 += a.x*b3.x + a.y*b3.y + a.z*b3.z + a.w*b3.w;
    }
    const float bc = bet_s[c];
    M_s[c][m0+0] = (m0+0 < c) ? bc*d0 : ((m0+0==c)?1.f:0.f);
    M_s[c][m0+1] = (m0+1 < c) ? bc*d1 : ((m0+1==c)?1.f:0.f);
    M_s[c][m0+2] = (m0+2 < c) ? bc*d2 : ((m0+2==c)?1.f:0.f);
    M_s[c][m0+3] = (m0+3 < c) ? bc*d3 : ((m0+3==c)?1.f:0.f);
  }
  __syncthreads();
  if (t < 32){
    const int j = t;
    for (int c=0;c<32;c++){
      float s = (c==j) ? 1.f : 0.f;
      for (int m=0;m<c;m++) s -= M_s[c][m]*T_s[m][j];
      T_s[c][j] = s;
    }
  }
  __syncthreads();
  {
    const int c = t >> 3, m0 = (t & 7)*4;
    #pragma unroll
    for (int x=0;x<4;x++) Tb_s[c][m0+x] = T_s[c][m0+x]*bet_s[m0+x];
  }
  __syncthreads();
  // w = Tb @ k_s (emit -w bf16, swizzled); u = Tb @ v_s (fp32)
  {
    const int colb = (t & 7)*4;
    float4 aw[8] = {};
    float4 au[8] = {};
    for (int m=0;m<32;m++){
      const float tb = Tb_s[row][m];
      #pragma unroll
      for (int y=0;y<8;y++){
        float4 kv = *(const float4*)&k_s[m][colb + y*32];
        float4 vv = *(const float4*)&v_s[m][colb + y*32];
        aw[y].x += tb*kv.x; aw[y].y += tb*kv.y; aw[y].z += tb*kv.z; aw[y].w += tb*kv.w;
        au[y].x += tb*vv.x; au[y].y += tb*vv.y; au[y].z += tb*vv.z; au[y].w += tb*vv.w;
      }
    }
    const size_t ob = (size_t)(n*32+row)*DMOD + h*DH + colb;
    #pragma unroll
    for (int y=0;y<8;y++){
      *(uint2*)&wng[cb + (size_t)row*256 + ((colb + y*32) ^ sw)] =
          make_uint2(pk2(-aw[y].x,-aw[y].y), pk2(-aw[y].z,-aw[y].w));
      *(float4*)(ubuf + ob + y*32) = au[y];
    }
  }
  // attn = tril(q k^T) bf16 [c][c']
  {
    const int c = t >> 3, m0 = (t & 7)*4;
    float d0=0.f,d1=0.f,d2=0.f,d3=0.f;
    for (int kk=0;kk<DH;kk+=4){
      float4 a  = *(const float4*)&q_s[c][kk];
      float4 b0 = *(const float4*)&k_s[m0+0][kk];
      float4 b1 = *(const float4*)&k_s[m0+1][kk];
      float4 b2 = *(const float4*)&k_s[m0+2][kk];
      float4 b3 = *(const float4*)&k_s[m0+3][kk];
      d0 += a.x*b0.x + a.y*b0.y + a.z*b0.z + a.w*b0.w;
      d1 += a.x*b1.x + a.y*b1.y + a.z*b1.z + a.w*b1.w;
      d2 += a.x*b2.x + a.y*b2.y + a.z*b2.z + a.w*b2.w;
      d3 += a.x*b3.x + a.y*b3.y + a.z*b3.z + a.w*b3.w;
    }
    d0 = (m0+0 <= c) ? d0 : 0.f;
    d1 = (m0+1 <= c) ? d1 : 0.f;
    d2 = (m0+2 <= c) ? d2 : 0.f;
    d3 = (m0+3 <= c) ? d3 : 0.f;
    *(uint2*)&atg[((size_t)(h*NCH+n)*32 + c)*32 + m0] =
        make_uint2(pk2(d0,d1), pk2(d2,d3));
  }
}

// ---------------- fused delta scan v2: counted-vmcnt pipeline ----------------
// grid (4 dv-quarters, 4 heads), 256 threads = 4 waves; wave owns dv-16 slice.
// Double-buffered flat LDS staged via global_load_lds; one raw barrier/chunk.
// stg layout per buffer: w[32][256]swz @0, q[32][256]swz @16384, kT[256][32] @32768,
//                        at[32][32] @49152, u f32[32][64] @51200; total 59392 B.
__global__ __launch_bounds__(256) void delta_scan_fused(
    const u16* __restrict__ qbg, const u16* __restrict__ wng,
    const u16* __restrict__ kTg, const u16* __restrict__ atg,
    const float* __restrict__ ubuf, float* __restrict__ dob)
{
  const int qd = blockIdx.x, h = blockIdx.y;
  const int t = threadIdx.x, lane = t & 63, wv = t >> 6;
  __shared__ __align__(16) unsigned char stg[2][59392];
  __shared__ __align__(16) u16 ST[4][16][264];
  __shared__ __align__(16) u16 uaT[4][16][40];

  const int g = lane >> 4, li = lane & 15;
  const int swz = (li & 7) << 3;

  f32x4 S[16];
  #pragma unroll
  for (int i=0;i<16;i++) S[i] = (f32x4){0.f,0.f,0.f,0.f};
  for (int i=lane; i<16*264; i+=64) (&ST[wv][0][0])[i] = 0;

  auto issue_stage = [&](int nn, int b){
    char* L2 = (char*)&stg[b][0];
    #pragma unroll
    for (int j=0;j<15;j++){
      int s = wv + 4*j; if (s >= 58) s = wv - 2;
      if (s < 50){
        const char* gsc;
        if (s < 16)      gsc = (const char*)wng + (size_t)(h*NCH+nn)*16384 + (size_t)s*1024;
        else if (s < 32) gsc = (const char*)qbg + (size_t)(h*NCH+nn)*16384 + (size_t)(s-16)*1024;
        else if (s < 48) gsc = (const char*)kTg + (size_t)(h*NCH+nn)*16384 + (size_t)(s-32)*1024;
        else             gsc = (const char*)atg + (size_t)(h*NCH+nn)*2048  + (size_t)(s-48)*1024;
        stage16(gsc + (size_t)lane*16, L2 + s*1024);
      } else {
        const int i = s - 50;
        stage16(ubuf + (size_t)(nn*32 + i*4 + (lane>>4))*DMOD + h*DH + qd*64 + (lane&15)*4,
                L2 + 51200 + i*1024);
      }
    }
  };

  issue_stage(0, 0);

  for (int n=0;n<NCH;n++){
    const int b = n & 1;
    asm volatile("s_waitcnt vmcnt(8)" ::: "memory");
    __builtin_amdgcn_s_barrier();
    __builtin_amdgcn_sched_barrier(0);
    issue_stage((n+1 < NCH) ? n+1 : NCH-1, b^1);

    const char* L = (const char*)&stg[b][0];
    const u16*  wl = (const u16*)(L);
    const u16*  ql = (const u16*)(L + 16384);
    const u16*  kl = (const u16*)(L + 32768);
    const u16*  al = (const u16*)(L + 49152);
    const float* ul = (const float*)(L + 51200);

    // ---- B-frags of S (wave-private shadow) ----
    bf16x8 Bs[8];
    #pragma unroll
    for (int kb=0;kb<8;kb++)
      Bs[kb] = *(const bf16x8*)&ST[wv][li][kb*32 + g*8];

    // ---- ua = u - w @ S_n  (A = -w swizzled; chain split 2x4) ----
    f32x4 ua0, ua1;
    #pragma unroll
    for (int r=0;r<4;r++){
      ua0[r] = ul[(g*4+r)*64 + wv*16+li];
      ua1[r] = ul[(16+g*4+r)*64 + wv*16+li];
    }
    f32x4 x0 = (f32x4){0.f,0.f,0.f,0.f}, x1 = (f32x4){0.f,0.f,0.f,0.f};
    #pragma unroll
    for (int kb=0;kb<4;kb++){
      const int idx = (kb*32 + g*8) ^ swz;
      bf16x8 a0 = *(const bf16x8*)&wl[(size_t)li*256 + idx];
      bf16x8 a1 = *(const bf16x8*)&wl[(size_t)(16+li)*256 + idx];
      ua0 = MFMA16(a0, Bs[kb], ua0);
      ua1 = MFMA16(a1, Bs[kb], ua1);
    }
    #pragma unroll
    for (int kb=4;kb<8;kb++){
      const int idx = (kb*32 + g*8) ^ swz;
      bf16x8 a0 = *(const bf16x8*)&wl[(size_t)li*256 + idx];
      bf16x8 a1 = *(const bf16x8*)&wl[(size_t)(16+li)*256 + idx];
      x0 = MFMA16(a0, Bs[kb], x0);
      x1 = MFMA16(a1, Bs[kb], x1);
    }
    #pragma unroll
    for (int r=0;r<4;r++){ ua0[r] += x0[r]; ua1[r] += x1[r]; }

    // ---- uaT roundtrip (wave-private) ----
    *(unsigned*)&uaT[wv][li][g*4]        = pk2(ua0[0], ua0[1]);
    *(unsigned*)&uaT[wv][li][g*4 + 2]    = pk2(ua0[2], ua0[3]);
    *(unsigned*)&uaT[wv][li][16 + g*4]   = pk2(ua1[0], ua1[1]);
    *(unsigned*)&uaT[wv][li][16 + g*4+2] = pk2(ua1[2], ua1[3]);
    bf16x8 bu = *(const bf16x8*)&uaT[wv][li][g*8];

    // ---- S += kT @ ua ----
    #pragma unroll
    for (int mt=0;mt<16;mt++){
      bf16x8 a = *(const bf16x8*)&kl[(size_t)(mt*16+li)*32 + g*8];
      S[mt] = MFMA16(a, bu, S[mt]);
    }

    // ---- o = q @ S_n + attn @ ua ----
    f32x4 o0 = (f32x4){0.f,0.f,0.f,0.f}, o1 = (f32x4){0.f,0.f,0.f,0.f};
    #pragma unroll
    for (int kb=0;kb<8;kb++){
      const int idx = (kb*32 + g*8) ^ swz;
      bf16x8 a0 = *(const bf16x8*)&ql[(size_t)li*256 + idx];
      bf16x8 a1 = *(const bf16x8*)&ql[(size_t)(16+li)*256 + idx];
      o0 = MFMA16(a0, Bs[kb], o0);
      o1 = MFMA16(a1, Bs[kb], o1);
    }
    {
      bf16x8 a0 = *(const bf16x8*)&al[(size_t)li*32 + g*8];
      bf16x8 a1 = *(const bf16x8*)&al[(size_t)(16+li)*32 + g*8];
      o0 = MFMA16(a0, bu, o0);
      o1 = MFMA16(a1, bu, o1);
    }

    // ---- refresh ST shadow (S_{n+1}) ----
    #pragma unroll
    for (int mt=0;mt<16;mt++){
      *(unsigned*)&ST[wv][li][mt*16 + g*4]     = pk2(S[mt][0], S[mt][1]);
      *(unsigned*)&ST[wv][li][mt*16 + g*4 + 2] = pk2(S[mt][2], S[mt][3]);
    }

    // ---- store o ----
    const size_t ob = (size_t)(n*32)*DMOD + h*DH + qd*64 + wv*16 + li;
    #pragma unroll
    for (int r=0;r<4;r++){
      dob[ob + (size_t)(g*4+r)*DMOD]    = o0[r];
      dob[ob + (size_t)(16+g*4+r)*DMOD] = o1[r];
    }
  }
}

// ---------------- transpose FIR filters to [j][c] ----------------
__global__ void prep_fir(const float* __restrict__ fs, const float* __restrict__ fm,
                         const float* __restrict__ fl, float* __restrict__ fts,
                         float* __restrict__ ftm, float* __restrict__ ftl)
{
  const int idx = blockIdx.x*256 + threadIdx.x;
  if (idx < 63*1024){
    const int j = idx >> 10, c = idx & 1023;
    ftl[idx] = fl[(size_t)c*63 + j];
  } else if (idx < 78*1024){
    const int r = idx - 63*1024;
    const int j = r >> 10, c = r & 1023;
    ftm[r] = fm[(size_t)c*15 + j];
  } else {
    const int r = idx - 78*1024;
    const int j = r >> 10, c = r & 1023;
    fts[r] = fs[(size_t)c*3 + j];
  }
}

// ---------------- FIR convs + gated mix + per-head RMSNorm (bf16 out) ----------------
__global__ __launch_bounds__(256) void fir_mix(
    const float* __restrict__ v, const float* __restrict__ dout,
    const float* __restrict__ probs, const float* __restrict__ ftl,
    const float* __restrict__ ftm, const float* __restrict__ fts,
    const float* __restrict__ normw, u16* __restrict__ omixb)
{
  const int i = blockIdx.x, h = blockIdx.y, dv = threadIdx.x;
  const int c = h*DH + dv;
  float accl = 0.f, accm = 0.f, accs = 0.f;
  {
    const int js = (i >= 62) ? 0 : (62 - i);
    for (int j=js;j<63;j++)
      accl += v[(size_t)(i-62+j)*DMOD + c] * ftl[(size_t)j*DMOD + c];
  }
  {
    const int js = (i >= 14) ? 0 : (14 - i);
    for (int j=js;j<15;j++)
      accm += v[(size_t)(i-14+j)*DMOD + c] * ftm[(size_t)j*DMOD + c];
  }
  {
    const int js = (i >= 2) ? 0 : (2 - i);
    for (int j=js;j<3;j++)
      accs += v[(size_t)(i-2+j)*DMOD + c] * fts[(size_t)j*DMOD + c];
  }
  const float* pr = probs + ((size_t)i*NH + h)*5;
  const float dvv = dout[(size_t)i*DMOD + c];
  const float vv  = v[(size_t)i*DMOD + c];
  float mix = pr[0]*accs + pr[1]*accm + pr[2]*accl + pr[3]*dvv + pr[4]*vv;
  float ss = mix*mix;
  #pragma unroll
  for (int m=1;m<64;m<<=1) ss += __shfl_xor(ss, m, 64);
  __shared__ float pr4[4];
  if ((threadIdx.x & 63) == 0) pr4[threadIdx.x >> 6] = ss;
  __syncthreads();
  const float tot = pr4[0]+pr4[1]+pr4[2]+pr4[3];
  const float o = mix * rsqrtf(tot*(1.f/256.f) + 1e-5f) * normw[dv];
  omixb[(size_t)i*DMOD + c] = f2bf(o);
}

// ---------------- launch ----------------
extern "C" void kernel_launch(void* const* d_in, const int* in_sizes, int n_in,
                              void* d_out, int out_size, void* d_ws, size_t ws_size,
                              hipStream_t stream)
{
  const float* hidden = (const float*)d_in[0];
  const float* Wq     = (const float*)d_in[1];
  const float* Wk     = (const float*)d_in[2];
  const float* Wv     = (const float*)d_in[3];
  const float* Wb     = (const float*)d_in[4];
  const float* convq  = (const float*)d_in[5];
  const float* convk  = (const float*)d_in[6];
  const float* convv  = (const float*)d_in[7];
  const float* firs   = (const float*)d_in[8];
  const float* firm   = (const float*)d_in[9];
  const float* firl   = (const float*)d_in[10];
  const float* gatew  = (const float*)d_in[11];
  const float* gateb  = (const float*)d_in[12];
  const float* logtemp= (const float*)d_in[13];
  const float* epsp   = (const float*)d_in[14];
  const float* normw  = (const float*)d_in[15];
  const float* Wo     = (const float*)d_in[16];
  float* out = (float*)d_out;

  char* W = (char*)d_ws;
  const size_t MB = (size_t)1 << 20;
  float* tmp   = (float*)(W + 0*MB);         // 8MB: pre-conv GEMM out; later u
  float* qb    = (float*)(W + 8*MB);         // 8MB; dob aliases after delta_pre
  float* dob   = (float*)(W + 8*MB);
  float* kb    = (float*)(W + 16*MB);        // 8MB; omixb aliases after delta_pre
  u16*   omixb = (u16*)  (W + 16*MB);
  float* vb    = (float*)(W + 24*MB);        // 8MB
  u16*   hidb  = (u16*)  (W + 32*MB);        // 4MB
  u16*   wqb   = (u16*)  (W + 36*MB);        // 2MB
  u16*   wkb   = (u16*)  (W + 38*MB);        // 2MB
  u16*   wvb   = (u16*)  (W + 40*MB);        // 2MB
  u16*   wob   = (u16*)  (W + 42*MB);        // 2MB
  u16*   qbg   = (u16*)  (W + 44*MB);        // 4MB
  u16*   wng   = (u16*)  (W + 48*MB);        // 4MB
  u16*   kTg   = (u16*)  (W + 52*MB);        // 4MB
  u16*   atg   = (u16*)  (W + 56*MB);        // 0.5MB
  float* betab = (float*)(W + 56*MB + 524288);            // 32KB
  float* probs = (float*)(W + 56*MB + 524288 + 32768);    // 160KB
  float* ftl   = (float*)(W + 57*MB);                     // 252KB
  float* ftm   = (float*)(W + 57*MB + 300*1024);          // 60KB
  float* fts   = (float*)(W + 57*MB + 380*1024);          // 12KB

  cvt_bf16<<<2048, 256, 0, stream>>>(hidden, hidb, 2048*1024/4);
  cvt_bf16<<<1024, 256, 0, stream>>>(Wq, wqb, 1024*1024/4);
  cvt_bf16<<<1024, 256, 0, stream>>>(Wk, wkb, 1024*1024/4);
  cvt_bf16<<<1024, 256, 0, stream>>>(Wv, wvb, 1024*1024/4);
  cvt_bf16<<<1024, 256, 0, stream>>>(Wo, wob, 1024*1024/4);
  prep_fir<<<324, 256, 0, stream>>>(firs, firm, firl, fts, ftm, ftl);

  gemm_bf16<<<dim3(16,8), 256, 0, stream>>>(hidb, wqb, tmp, LSEQ, DMOD, DMOD);
  conv_silu<<<8192, 256, 0, stream>>>(tmp, convq, qb);
  gemm_bf16<<<dim3(16,8), 256, 0, stream>>>(hidb, wkb, tmp, LSEQ, DMOD, DMOD);
  conv_silu<<<8192, 256, 0, stream>>>(tmp, convk, kb);
  gemm_bf16<<<dim3(16,8), 256, 0, stream>>>(hidb, wvb, tmp, LSEQ, DMOD, DMOD);
  conv_silu<<<8192, 256, 0, stream>>>(tmp, convv, vb);

  beta_gate<<<2048, 256, 0, stream>>>(hidden, Wb, gatew, gateb, logtemp, epsp, betab, probs);

  delta_pre<<<dim3(64,4), 256, 0, stream>>>(qb, kb, vb, betab, qbg, wng, kTg, atg, tmp);
  delta_scan_fused<<<dim3(4,4), 256, 0, stream>>>(qbg, wng, kTg, atg, tmp, dob);

  fir_mix<<<dim3(2048,4), 256, 0, stream>>>(vb, dob, probs, ftl, ftm, fts, normw, omixb);

  gemm_bf16<<<dim3(16,8), 256, 0, stream>>>(omixb, wob, out, LSEQ, DMOD, DMOD);
}

// Round 4
// 505.178 us; speedup vs baseline: 2.5529x; 1.0587x over previous
//
#include <hip/hip_runtime.h>

#define LSEQ 2048
#define DMOD 1024
#define NH   4
#define DH   256
#define NCH  64
#define CPAD 260

typedef unsigned short u16;
typedef short bf16x8 __attribute__((ext_vector_type(8)));
typedef float f32x4  __attribute__((ext_vector_type(4)));

#define MFMA16(a,b,c) __builtin_amdgcn_mfma_f32_16x16x32_bf16((a),(b),(c),0,0,0)

__device__ __forceinline__ float sigf(float x){ return 1.0f/(1.0f + expf(-x)); }

__device__ __forceinline__ u16 f2bf(float f){
  unsigned u = __float_as_uint(f);
  return (u16)((u + 0x7FFFu + ((u>>16)&1u)) >> 16);
}
__device__ __forceinline__ unsigned pk2(float a, float b){
  return (unsigned)f2bf(a) | ((unsigned)f2bf(b) << 16);
}

__device__ __forceinline__ void stage16(const void* g, void* l){
  __builtin_amdgcn_global_load_lds((const __attribute__((address_space(1))) unsigned*)g,
                                   (__attribute__((address_space(3))) unsigned*)l, 16, 0, 0);
}

// ---------------- fp32 -> bf16 convert ----------------
__global__ __launch_bounds__(256) void cvt_bf16(const float* __restrict__ src,
                                                u16* __restrict__ dst, int n4){
  int i = blockIdx.x*256 + threadIdx.x;
  if (i < n4){
    float4 v = ((const float4*)src)[i];
    ((uint2*)dst)[i] = make_uint2(pk2(v.x,v.y), pk2(v.z,v.w));
  }
}

// ---------------- bf16 MFMA GEMM: C[M][N]f32 = A[M][K] @ B[N][K]^T ----------------
__global__ __launch_bounds__(256) void gemm_bf16(
    const u16* __restrict__ A, const u16* __restrict__ B,
    float* __restrict__ C, int M, int N, int K)
{
  __shared__ __align__(16) u16 Asl[2][128][32];
  __shared__ __align__(16) u16 Bsl[2][128][32];
  const int i0 = blockIdx.x*128, j0 = blockIdx.y*128;
  const int t = threadIdx.x, lane = t & 63, wv = t >> 6;
  const int wm = wv >> 1, wn = wv & 1;
  const int li = lane & 15, g = lane >> 4;
  const int lr = lane >> 2, lc = lane & 3;
  f32x4 acc[4][4] = {};

  auto stageAB = [&](int buf, int kt){
    const int k0 = kt*32;
    #pragma unroll
    for (int c2=0;c2<2;c2++){
      const int row = wv*32 + c2*16 + lr;
      stage16(A + (size_t)(i0+row)*K + k0 + lc*8, &Asl[buf][wv*32 + c2*16][0]);
      stage16(B + (size_t)(j0+row)*K + k0 + lc*8, &Bsl[buf][wv*32 + c2*16][0]);
    }
  };

  int buf = 0;
  const int nk = K/32;
  stageAB(0, 0);
  for (int kt=0; kt<nk; kt++){
    __syncthreads();
    if (kt+1 < nk) stageAB(buf^1, kt+1);
    bf16x8 af[4], bf[4];
    #pragma unroll
    for (int mt=0;mt<4;mt++) af[mt] = *(const bf16x8*)&Asl[buf][wm*64+mt*16+li][g*8];
    #pragma unroll
    for (int nt=0;nt<4;nt++) bf[nt] = *(const bf16x8*)&Bsl[buf][wn*64+nt*16+li][g*8];
    #pragma unroll
    for (int mt=0;mt<4;mt++)
      #pragma unroll
      for (int nt=0;nt<4;nt++)
        acc[mt][nt] = MFMA16(af[mt], bf[nt], acc[mt][nt]);
    buf ^= 1;
  }
  #pragma unroll
  for (int mt=0;mt<4;mt++){
    #pragma unroll
    for (int nt=0;nt<4;nt++){
      #pragma unroll
      for (int r=0;r<4;r++){
        const int row = i0 + wm*64 + mt*16 + g*4 + r;
        const int col = j0 + wn*64 + nt*16 + li;
        C[(size_t)row*N + col] = acc[mt][nt][r];
      }
    }
  }
}

// ---------------- depthwise causal conv (K=4) + silu ----------------
__global__ __launch_bounds__(256) void conv_silu(
    const float* __restrict__ x, const float* __restrict__ w, float* __restrict__ y)
{
  const int idx = blockIdx.x*256 + threadIdx.x;
  const int c = idx & (DMOD-1);
  const int i = idx >> 10;
  float4 wc = *(const float4*)(w + (size_t)c*4);
  float acc = wc.w * x[idx];
  if (i >= 1) acc += wc.z * x[idx -   DMOD];
  if (i >= 2) acc += wc.y * x[idx - 2*DMOD];
  if (i >= 3) acc += wc.x * x[idx - 3*DMOD];
  y[idx] = acc * sigf(acc);
}

// ---------------- beta (sigmoid) + 5-way gate probs per row ----------------
__global__ __launch_bounds__(256) void beta_gate(
    const float* __restrict__ hidden, const float* __restrict__ Wb,
    const float* __restrict__ gw, const float* __restrict__ gb,
    const float* __restrict__ logtemp, const float* __restrict__ epsp,
    float* __restrict__ betab, float* __restrict__ probs)
{
  const int i = blockIdx.x, t = threadIdx.x;
  float4 h4 = *(const float4*)(hidden + (size_t)i*DMOD + t*4);
  float part[24];
  #pragma unroll
  for (int o=0;o<24;o++){
    const float* wr = (o<4) ? (Wb + (size_t)o*DMOD) : (gw + (size_t)(o-4)*DMOD);
    float4 w4 = *(const float4*)(wr + t*4);
    part[o] = h4.x*w4.x + h4.y*w4.y + h4.z*w4.z + h4.w*w4.w;
  }
  __shared__ float red[24][4];
  __shared__ float fin[24];
  const int lane = t & 63, wv = t >> 6;
  #pragma unroll
  for (int o=0;o<24;o++){
    float vv = part[o];
    #pragma unroll
    for (int m=1;m<64;m<<=1) vv += __shfl_xor(vv, m, 64);
    if (lane == 0) red[o][wv] = vv;
  }
  __syncthreads();
  if (t < 24) fin[t] = red[t][0]+red[t][1]+red[t][2]+red[t][3];
  __syncthreads();
  if (t < NH){
    const int hh = t;
    betab[(size_t)i*NH + hh] = sigf(fin[hh]);
    float temp = expf(logtemp[hh]);
    float lg[5], mx = -1e30f;
    #pragma unroll
    for (int p=0;p<5;p++){ lg[p] = (fin[4+hh*5+p] + gb[hh*5+p]) / temp; mx = fmaxf(mx, lg[p]); }
    float ex[5], s = 0.f;
    #pragma unroll
    for (int p=0;p<5;p++){ ex[p] = expf(lg[p]-mx); s += ex[p]; }
    float eps = fminf(fmaxf(epsp[hh], 0.f), 0.2f);
    #pragma unroll
    for (int p=0;p<5;p++) probs[((size_t)i*NH+hh)*5 + p] = (ex[p]/s)*(1.f-5.f*eps) + eps;
  }
}

// ---------------- delta precompute: per (chunk, head) ----------------
// emits bf16 MFMA-ready operands: q,-w row-major XOR-SWIZZLED (idx ^= (row&7)<<3),
// kT [dk][c], attn [c][c'], u fp32.
__global__ __launch_bounds__(256) void delta_pre(
    const float* __restrict__ q, const float* __restrict__ k, const float* __restrict__ v,
    const float* __restrict__ beta,
    u16* __restrict__ qbg, u16* __restrict__ wng, u16* __restrict__ kTg,
    u16* __restrict__ atg, float* __restrict__ ubuf)
{
  const int n = blockIdx.x, h = blockIdx.y;
  const int t = threadIdx.x;
  __shared__ float q_s[32][CPAD], k_s[32][CPAD], v_s[32][CPAD];
  __shared__ float T_s[32][32], Tb_s[32][32], M_s[32][32];
  __shared__ float rr[2][32][8];
  __shared__ float scl[2][32];
  __shared__ float bet_s[32];

  const int row = t >> 3, cq = t & 7;
  const size_t gb = (size_t)(n*32+row)*DMOD + h*DH + cq*32;
  const size_t cb = (size_t)(h*NCH+n)*32*256;
  const int sw = (row & 7) << 3;               // global-side swizzle for q/w
  float psq = 0.f, psk = 0.f;
  #pragma unroll
  for (int x=0;x<8;x++){
    float4 qa = *(const float4*)(q + gb + x*4);
    float4 ka = *(const float4*)(k + gb + x*4);
    float4 va = *(const float4*)(v + gb + x*4);
    *(float4*)&q_s[row][cq*32+x*4] = qa;
    *(float4*)&k_s[row][cq*32+x*4] = ka;
    *(float4*)&v_s[row][cq*32+x*4] = va;
    psq += qa.x*qa.x+qa.y*qa.y+qa.z*qa.z+qa.w*qa.w;
    psk += ka.x*ka.x+ka.y*ka.y+ka.z*ka.z+ka.w*ka.w;
  }
  rr[0][row][cq] = psq; rr[1][row][cq] = psk;
  if (t < 32) bet_s[t] = beta[(size_t)(n*32+t)*NH + h];
  __syncthreads();
  if (t < 64){
    const int wh = t >> 5, r = t & 31;
    float s = 1e-6f;
    #pragma unroll
    for (int x=0;x<8;x++) s += rr[wh][r][x];
    scl[wh][r] = rsqrtf(s);
  }
  __syncthreads();
  {
    const float sq = scl[0][row], sk2 = scl[1][row];
    #pragma unroll
    for (int x=0;x<8;x++){
      float4 qa = *(float4*)&q_s[row][cq*32+x*4];
      qa.x*=sq; qa.y*=sq; qa.z*=sq; qa.w*=sq;
      *(float4*)&q_s[row][cq*32+x*4] = qa;
      *(uint2*)&qbg[cb + (size_t)row*256 + ((cq*32 + x*4) ^ sw)] =
          make_uint2(pk2(qa.x,qa.y), pk2(qa.z,qa.w));
      float4 ka = *(float4*)&k_s[row][cq*32+x*4];
      ka.x*=sk2; ka.y*=sk2; ka.z*=sk2; ka.w*=sk2;
      *(float4*)&k_s[row][cq*32+x*4] = ka;
    }
  }
  __syncthreads();
  // kT bf16 [dk=256][c=32]
  {
    unsigned* kp = (unsigned*)(kTg + ((size_t)(h*NCH+n)*256 + t)*32);
    #pragma unroll
    for (int c2=0;c2<16;c2++)
      kp[c2] = pk2(k_s[2*c2][t], k_s[2*c2+1][t]);
  }
  // M matrix
  {
    const int c = t >> 3, m0 = (t & 7)*4;
    float d0=0.f,d1=0.f,d2=0.f,d3=0.f;
    for (int kk=0;kk<DH;kk+=4){
      float4 a  = *(const float4*)&k_s[c][kk];
      float4 b0 = *(const float4*)&k_s[m0+0][kk];
      float4 b1 = *(const float4*)&k_s[m0+1][kk];
      float4 b2 = *(const float4*)&k_s[m0+2][kk];
      float4 b3 = *(const float4*)&k_s[m0+3][kk];
      d0 += a.x*b0.x + a.y*b0.y + a.z*b0.z + a.w*b0.w;
      d1 += a.x*b1.x + a.y*b1.y + a.z*b1.z + a.w*b1.w;
      d2 += a.x*b2.x + a.y*b2.y + a.z*b2.z + a.w*b2.w;
      d3 += a.x*b3.x + a.y*b3.y + a.z*b3.z + a.w*b3.w;
    }
    const float bc = bet_s[c];
    M_s[c][m0+0] = (m0+0 < c) ? bc*d0 : ((m0+0==c)?1.f:0.f);
    M_s[c][m0+1] = (m0+1 < c) ? bc*d1 : ((m0+1==c)?1.f:0.f);
    M_s[c][m0+2] = (m0+2 < c) ? bc*d2 : ((m0+2==c)?1.f:0.f);
    M_s[c][m0+3] = (m0+3 < c) ? bc*d3 : ((m0+3==c)?1.f:0.f);
  }
  __syncthreads();
  if (t < 32){
    const int j = t;
    for (int c=0;c<32;c++){
      float s = (c==j) ? 1.f : 0.f;
      for (int m=0;m<c;m++) s -= M_s[c][m]*T_s[m][j];
      T_s[c][j] = s;
    }
  }
  __syncthreads();
  {
    const int c = t >> 3, m0 = (t & 7)*4;
    #pragma unroll
    for (int x=0;x<4;x++) Tb_s[c][m0+x] = T_s[c][m0+x]*bet_s[m0+x];
  }
  __syncthreads();
  // w = Tb @ k_s (emit -w bf16, swizzled); u = Tb @ v_s (fp32)
  {
    const int colb = (t & 7)*4;
    float4 aw[8] = {};
    float4 au[8] = {};
    for (int m=0;m<32;m++){
      const float tb = Tb_s[row][m];
      #pragma unroll
      for (int y=0;y<8;y++){
        float4 kv = *(const float4*)&k_s[m][colb + y*32];
        float4 vv = *(const float4*)&v_s[m][colb + y*32];
        aw[y].x += tb*kv.x; aw[y].y += tb*kv.y; aw[y].z += tb*kv.z; aw[y].w += tb*kv.w;
        au[y].x += tb*vv.x; au[y].y += tb*vv.y; au[y].z += tb*vv.z; au[y].w += tb*vv.w;
      }
    }
    const size_t ob = (size_t)(n*32+row)*DMOD + h*DH + colb;
    #pragma unroll
    for (int y=0;y<8;y++){
      *(uint2*)&wng[cb + (size_t)row*256 + ((colb + y*32) ^ sw)] =
          make_uint2(pk2(-aw[y].x,-aw[y].y), pk2(-aw[y].z,-aw[y].w));
      *(float4*)(ubuf + ob + y*32) = au[y];
    }
  }
  // attn = tril(q k^T) bf16 [c][c']
  {
    const int c = t >> 3, m0 = (t & 7)*4;
    float d0=0.f,d1=0.f,d2=0.f,d3=0.f;
    for (int kk=0;kk<DH;kk+=4){
      float4 a  = *(const float4*)&q_s[c][kk];
      float4 b0 = *(const float4*)&k_s[m0+0][kk];
      float4 b1 = *(const float4*)&k_s[m0+1][kk];
      float4 b2 = *(const float4*)&k_s[m0+2][kk];
      float4 b3 = *(const float4*)&k_s[m0+3][kk];
      d0 += a.x*b0.x + a.y*b0.y + a.z*b0.z + a.w*b0.w;
      d1 += a.x*b1.x + a.y*b1.y + a.z*b1.z + a.w*b1.w;
      d2 += a.x*b2.x + a.y*b2.y + a.z*b2.z + a.w*b2.w;
      d3 += a.x*b3.x + a.y*b3.y + a.z*b3.z + a.w*b3.w;
    }
    d0 = (m0+0 <= c) ? d0 : 0.f;
    d1 = (m0+1 <= c) ? d1 : 0.f;
    d2 = (m0+2 <= c) ? d2 : 0.f;
    d3 = (m0+3 <= c) ? d3 : 0.f;
    *(uint2*)&atg[((size_t)(h*NCH+n)*32 + c)*32 + m0] =
        make_uint2(pk2(d0,d1), pk2(d2,d3));
  }
}

// ---------------- fused delta scan v3: ONE WAVE per block, no barriers ----------------
// grid (16 dv-slices, 4 heads) = 64 blocks x 64 threads. Wave owns dv-16 slice;
// S[256][16] in 64 VGPRs. Double-buffered LDS staging via global_load_lds,
// counted vmcnt; all LDS wave-private -> zero barriers.
// stg layout per buffer: w[32][256]swz @0 (16K), q @16384 (16K), kT[256][32] @32768 (16K),
//                        at[32][32] @49152 (2K), u f32[32][16] @51200 (2K); 53248 B total.
__global__ __launch_bounds__(64) void delta_scan_fused(
    const u16* __restrict__ qbg, const u16* __restrict__ wng,
    const u16* __restrict__ kTg, const u16* __restrict__ atg,
    const float* __restrict__ ubuf, float* __restrict__ dob)
{
  const int qd = blockIdx.x, h = blockIdx.y;
  const int lane = threadIdx.x;
  __shared__ __align__(16) unsigned char stg[2][53248];
  __shared__ __align__(16) u16 ST[16][264];
  __shared__ __align__(16) u16 uaT[16][40];

  const int g = lane >> 4, li = lane & 15;
  const int swz = (li & 7) << 3;

  f32x4 S[16];
  #pragma unroll
  for (int i=0;i<16;i++) S[i] = (f32x4){0.f,0.f,0.f,0.f};
  for (int i=lane; i<16*264; i+=64) (&ST[0][0])[i] = 0;

  auto issue_stage = [&](int nn, int b){
    char* L = (char*)&stg[b][0];
    const size_t cbB = (size_t)(h*NCH+nn)*16384;   // byte base for w/q/kT chunks
    #pragma unroll
    for (int j=0;j<16;j++){
      stage16((const char*)wng + cbB + j*1024 + (size_t)lane*16, L + j*1024);
      stage16((const char*)qbg + cbB + j*1024 + (size_t)lane*16, L + 16384 + j*1024);
      stage16((const char*)kTg + cbB + j*1024 + (size_t)lane*16, L + 32768 + j*1024);
    }
    stage16((const char*)atg + (size_t)(h*NCH+nn)*2048 +        (size_t)lane*16, L + 49152);
    stage16((const char*)atg + (size_t)(h*NCH+nn)*2048 + 1024 + (size_t)lane*16, L + 50176);
    #pragma unroll
    for (int i=0;i<2;i++)
      stage16(ubuf + (size_t)(nn*32 + i*16 + (lane>>2))*DMOD + h*DH + qd*16 + (lane&3)*4,
              L + 51200 + i*1024);
  };

  issue_stage(0, 0);

  for (int n=0;n<NCH;n++){
    const int b = n & 1;
    if (n) { asm volatile("s_waitcnt vmcnt(8)" ::: "memory"); }
    else   { asm volatile("s_waitcnt vmcnt(0)" ::: "memory"); }
    asm volatile("s_waitcnt lgkmcnt(0)" ::: "memory");
    __builtin_amdgcn_sched_barrier(0);
    issue_stage((n+1 < NCH) ? n+1 : NCH-1, b^1);

    const char* L = (const char*)&stg[b][0];
    const u16*  wl = (const u16*)(L);
    const u16*  ql = (const u16*)(L + 16384);
    const u16*  kl = (const u16*)(L + 32768);
    const u16*  al = (const u16*)(L + 49152);
    const float* ul = (const float*)(L + 51200);

    // ---- B-frags of S shadow ----
    bf16x8 Bs[8];
    #pragma unroll
    for (int kb=0;kb<8;kb++)
      Bs[kb] = *(const bf16x8*)&ST[li][kb*32 + g*8];

    // ---- ua = u - w @ S_n  (A = -w swizzled; chain split 2x4) ----
    f32x4 ua0, ua1;
    #pragma unroll
    for (int r=0;r<4;r++){
      ua0[r] = ul[(g*4+r)*16 + li];
      ua1[r] = ul[(16+g*4+r)*16 + li];
    }
    f32x4 x0 = (f32x4){0.f,0.f,0.f,0.f}, x1 = (f32x4){0.f,0.f,0.f,0.f};
    #pragma unroll
    for (int kb=0;kb<4;kb++){
      const int idx = (kb*32 + g*8) ^ swz;
      bf16x8 a0 = *(const bf16x8*)&wl[(size_t)li*256 + idx];
      bf16x8 a1 = *(const bf16x8*)&wl[(size_t)(16+li)*256 + idx];
      ua0 = MFMA16(a0, Bs[kb], ua0);
      ua1 = MFMA16(a1, Bs[kb], ua1);
    }
    #pragma unroll
    for (int kb=4;kb<8;kb++){
      const int idx = (kb*32 + g*8) ^ swz;
      bf16x8 a0 = *(const bf16x8*)&wl[(size_t)li*256 + idx];
      bf16x8 a1 = *(const bf16x8*)&wl[(size_t)(16+li)*256 + idx];
      x0 = MFMA16(a0, Bs[kb], x0);
      x1 = MFMA16(a1, Bs[kb], x1);
    }
    #pragma unroll
    for (int r=0;r<4;r++){ ua0[r] += x0[r]; ua1[r] += x1[r]; }

    // ---- uaT roundtrip (wave-private) ----
    *(unsigned*)&uaT[li][g*4]        = pk2(ua0[0], ua0[1]);
    *(unsigned*)&uaT[li][g*4 + 2]    = pk2(ua0[2], ua0[3]);
    *(unsigned*)&uaT[li][16 + g*4]   = pk2(ua1[0], ua1[1]);
    *(unsigned*)&uaT[li][16 + g*4+2] = pk2(ua1[2], ua1[3]);
    bf16x8 bu = *(const bf16x8*)&uaT[li][g*8];

    // ---- S += kT @ ua ----
    #pragma unroll
    for (int mt=0;mt<16;mt++){
      bf16x8 a = *(const bf16x8*)&kl[(size_t)(mt*16+li)*32 + g*8];
      S[mt] = MFMA16(a, bu, S[mt]);
    }

    // ---- o = q @ S_n + attn @ ua ----
    f32x4 o0 = (f32x4){0.f,0.f,0.f,0.f}, o1 = (f32x4){0.f,0.f,0.f,0.f};
    #pragma unroll
    for (int kb=0;kb<8;kb++){
      const int idx = (kb*32 + g*8) ^ swz;
      bf16x8 a0 = *(const bf16x8*)&ql[(size_t)li*256 + idx];
      bf16x8 a1 = *(const bf16x8*)&ql[(size_t)(16+li)*256 + idx];
      o0 = MFMA16(a0, Bs[kb], o0);
      o1 = MFMA16(a1, Bs[kb], o1);
    }
    {
      bf16x8 a0 = *(const bf16x8*)&al[(size_t)li*32 + g*8];
      bf16x8 a1 = *(const bf16x8*)&al[(size_t)(16+li)*32 + g*8];
      o0 = MFMA16(a0, bu, o0);
      o1 = MFMA16(a1, bu, o1);
    }

    // ---- refresh ST shadow (S_{n+1}) ----
    #pragma unroll
    for (int mt=0;mt<16;mt++){
      *(unsigned*)&ST[li][mt*16 + g*4]     = pk2(S[mt][0], S[mt][1]);
      *(unsigned*)&ST[li][mt*16 + g*4 + 2] = pk2(S[mt][2], S[mt][3]);
    }

    // ---- store o ----
    const size_t ob = (size_t)(n*32)*DMOD + h*DH + qd*16 + li;
    #pragma unroll
    for (int r=0;r<4;r++){
      dob[ob + (size_t)(g*4+r)*DMOD]    = o0[r];
      dob[ob + (size_t)(16+g*4+r)*DMOD] = o1[r];
    }
  }
}

// ---------------- transpose FIR filters to [j][c] ----------------
__global__ void prep_fir(const float* __restrict__ fs, const float* __restrict__ fm,
                         const float* __restrict__ fl, float* __restrict__ fts,
                         float* __restrict__ ftm, float* __restrict__ ftl)
{
  const int idx = blockIdx.x*256 + threadIdx.x;
  if (idx < 63*1024){
    const int j = idx >> 10, c = idx & 1023;
    ftl[idx] = fl[(size_t)c*63 + j];
  } else if (idx < 78*1024){
    const int r = idx - 63*1024;
    const int j = r >> 10, c = r & 1023;
    ftm[r] = fm[(size_t)c*15 + j];
  } else {
    const int r = idx - 78*1024;
    const int j = r >> 10, c = r & 1023;
    fts[r] = fs[(size_t)c*3 + j];
  }
}

// ---------------- FIR convs + gated mix + per-head RMSNorm (bf16 out) ----------------
__global__ __launch_bounds__(256) void fir_mix(
    const float* __restrict__ v, const float* __restrict__ dout,
    const float* __restrict__ probs, const float* __restrict__ ftl,
    const float* __restrict__ ftm, const float* __restrict__ fts,
    const float* __restrict__ normw, u16* __restrict__ omixb)
{
  const int i = blockIdx.x, h = blockIdx.y, dv = threadIdx.x;
  const int c = h*DH + dv;
  float accl = 0.f, accm = 0.f, accs = 0.f;
  {
    const int js = (i >= 62) ? 0 : (62 - i);
    for (int j=js;j<63;j++)
      accl += v[(size_t)(i-62+j)*DMOD + c] * ftl[(size_t)j*DMOD + c];
  }
  {
    const int js = (i >= 14) ? 0 : (14 - i);
    for (int j=js;j<15;j++)
      accm += v[(size_t)(i-14+j)*DMOD + c] * ftm[(size_t)j*DMOD + c];
  }
  {
    const int js = (i >= 2) ? 0 : (2 - i);
    for (int j=js;j<3;j++)
      accs += v[(size_t)(i-2+j)*DMOD + c] * fts[(size_t)j*DMOD + c];
  }
  const float* pr = probs + ((size_t)i*NH + h)*5;
  const float dvv = dout[(size_t)i*DMOD + c];
  const float vv  = v[(size_t)i*DMOD + c];
  float mix = pr[0]*accs + pr[1]*accm + pr[2]*accl + pr[3]*dvv + pr[4]*vv;
  float ss = mix*mix;
  #pragma unroll
  for (int m=1;m<64;m<<=1) ss += __shfl_xor(ss, m, 64);
  __shared__ float pr4[4];
  if ((threadIdx.x & 63) == 0) pr4[threadIdx.x >> 6] = ss;
  __syncthreads();
  const float tot = pr4[0]+pr4[1]+pr4[2]+pr4[3];
  const float o = mix * rsqrtf(tot*(1.f/256.f) + 1e-5f) * normw[dv];
  omixb[(size_t)i*DMOD + c] = f2bf(o);
}

// ---------------- launch ----------------
extern "C" void kernel_launch(void* const* d_in, const int* in_sizes, int n_in,
                              void* d_out, int out_size, void* d_ws, size_t ws_size,
                              hipStream_t stream)
{
  const float* hidden = (const float*)d_in[0];
  const float* Wq     = (const float*)d_in[1];
  const float* Wk     = (const float*)d_in[2];
  const float* Wv     = (const float*)d_in[3];
  const float* Wb     = (const float*)d_in[4];
  const float* convq  = (const float*)d_in[5];
  const float* convk  = (const float*)d_in[6];
  const float* convv  = (const float*)d_in[7];
  const float* firs   = (const float*)d_in[8];
  const float* firm   = (const float*)d_in[9];
  const float* firl   = (const float*)d_in[10];
  const float* gatew  = (const float*)d_in[11];
  const float* gateb  = (const float*)d_in[12];
  const float* logtemp= (const float*)d_in[13];
  const float* epsp   = (const float*)d_in[14];
  const float* normw  = (const float*)d_in[15];
  const float* Wo     = (const float*)d_in[16];
  float* out = (float*)d_out;

  char* W = (char*)d_ws;
  const size_t MB = (size_t)1 << 20;
  float* tmp   = (float*)(W + 0*MB);         // 8MB: pre-conv GEMM out; later u
  float* qb    = (float*)(W + 8*MB);         // 8MB; dob aliases after delta_pre
  float* dob   = (float*)(W + 8*MB);
  float* kb    = (float*)(W + 16*MB);        // 8MB; omixb aliases after delta_pre
  u16*   omixb = (u16*)  (W + 16*MB);
  float* vb    = (float*)(W + 24*MB);        // 8MB
  u16*   hidb  = (u16*)  (W + 32*MB);        // 4MB
  u16*   wqb   = (u16*)  (W + 36*MB);        // 2MB
  u16*   wkb   = (u16*)  (W + 38*MB);        // 2MB
  u16*   wvb   = (u16*)  (W + 40*MB);        // 2MB
  u16*   wob   = (u16*)  (W + 42*MB);        // 2MB
  u16*   qbg   = (u16*)  (W + 44*MB);        // 4MB
  u16*   wng   = (u16*)  (W + 48*MB);        // 4MB
  u16*   kTg   = (u16*)  (W + 52*MB);        // 4MB
  u16*   atg   = (u16*)  (W + 56*MB);        // 0.5MB
  float* betab = (float*)(W + 56*MB + 524288);            // 32KB
  float* probs = (float*)(W + 56*MB + 524288 + 32768);    // 160KB
  float* ftl   = (float*)(W + 57*MB);                     // 252KB
  float* ftm   = (float*)(W + 57*MB + 300*1024);          // 60KB
  float* fts   = (float*)(W + 57*MB + 380*1024);          // 12KB

  cvt_bf16<<<2048, 256, 0, stream>>>(hidden, hidb, 2048*1024/4);
  cvt_bf16<<<1024, 256, 0, stream>>>(Wq, wqb, 1024*1024/4);
  cvt_bf16<<<1024, 256, 0, stream>>>(Wk, wkb, 1024*1024/4);
  cvt_bf16<<<1024, 256, 0, stream>>>(Wv, wvb, 1024*1024/4);
  cvt_bf16<<<1024, 256, 0, stream>>>(Wo, wob, 1024*1024/4);
  prep_fir<<<324, 256, 0, stream>>>(firs, firm, firl, fts, ftm, ftl);

  gemm_bf16<<<dim3(16,8), 256, 0, stream>>>(hidb, wqb, tmp, LSEQ, DMOD, DMOD);
  conv_silu<<<8192, 256, 0, stream>>>(tmp, convq, qb);
  gemm_bf16<<<dim3(16,8), 256, 0, stream>>>(hidb, wkb, tmp, LSEQ, DMOD, DMOD);
  conv_silu<<<8192, 256, 0, stream>>>(tmp, convk, kb);
  gemm_bf16<<<dim3(16,8), 256, 0, stream>>>(hidb, wvb, tmp, LSEQ, DMOD, DMOD);
  conv_silu<<<8192, 256, 0, stream>>>(tmp, convv, vb);

  beta_gate<<<2048, 256, 0, stream>>>(hidden, Wb, gatew, gateb, logtemp, epsp, betab, probs);

  delta_pre<<<dim3(64,4), 256, 0, stream>>>(qb, kb, vb, betab, qbg, wng, kTg, atg, tmp);
  delta_scan_fused<<<dim3(16,4), 64, 0, stream>>>(qbg, wng, kTg, atg, tmp, dob);

  fir_mix<<<dim3(2048,4), 256, 0, stream>>>(vb, dob, probs, ftl, ftm, fts, normw, omixb);

  gemm_bf16<<<dim3(16,8), 256, 0, stream>>>(omixb, wob, out, LSEQ, DMOD, DMOD);
}

// Round 5
// 476.413 us; speedup vs baseline: 2.7071x; 1.0604x over previous
//
#include <hip/hip_runtime.h>

#define LSEQ 2048
#define DMOD 1024
#define NH   4
#define DH   256
#define NCH  64
#define CPAD 260

typedef unsigned short u16;
typedef short bf16x8 __attribute__((ext_vector_type(8)));
typedef float f32x4  __attribute__((ext_vector_type(4)));

#define MFMA16(a,b,c) __builtin_amdgcn_mfma_f32_16x16x32_bf16((a),(b),(c),0,0,0)

__device__ __forceinline__ float sigf(float x){ return 1.0f/(1.0f + expf(-x)); }

__device__ __forceinline__ u16 f2bf(float f){
  unsigned u = __float_as_uint(f);
  return (u16)((u + 0x7FFFu + ((u>>16)&1u)) >> 16);
}
__device__ __forceinline__ unsigned pk2(float a, float b){
  return (unsigned)f2bf(a) | ((unsigned)f2bf(b) << 16);
}

__device__ __forceinline__ void stage16(const void* g, void* l){
  __builtin_amdgcn_global_load_lds((const __attribute__((address_space(1))) unsigned*)g,
                                   (__attribute__((address_space(3))) unsigned*)l, 16, 0, 0);
}

// ---------------- fp32 -> bf16 convert ----------------
__global__ __launch_bounds__(256) void cvt_bf16(const float* __restrict__ src,
                                                u16* __restrict__ dst, int n4){
  int i = blockIdx.x*256 + threadIdx.x;
  if (i < n4){
    float4 v = ((const float4*)src)[i];
    ((uint2*)dst)[i] = make_uint2(pk2(v.x,v.y), pk2(v.z,v.w));
  }
}

// ---------------- bf16 MFMA GEMM: C[M][N]f32 = A[M][K] @ B[N][K]^T ----------------
__global__ __launch_bounds__(256) void gemm_bf16(
    const u16* __restrict__ A, const u16* __restrict__ B,
    float* __restrict__ C, int M, int N, int K)
{
  __shared__ __align__(16) u16 Asl[2][128][32];
  __shared__ __align__(16) u16 Bsl[2][128][32];
  const int i0 = blockIdx.x*128, j0 = blockIdx.y*128;
  const int t = threadIdx.x, lane = t & 63, wv = t >> 6;
  const int wm = wv >> 1, wn = wv & 1;
  const int li = lane & 15, g = lane >> 4;
  const int lr = lane >> 2, lc = lane & 3;
  f32x4 acc[4][4] = {};

  auto stageAB = [&](int buf, int kt){
    const int k0 = kt*32;
    #pragma unroll
    for (int c2=0;c2<2;c2++){
      const int row = wv*32 + c2*16 + lr;
      stage16(A + (size_t)(i0+row)*K + k0 + lc*8, &Asl[buf][wv*32 + c2*16][0]);
      stage16(B + (size_t)(j0+row)*K + k0 + lc*8, &Bsl[buf][wv*32 + c2*16][0]);
    }
  };

  int buf = 0;
  const int nk = K/32;
  stageAB(0, 0);
  for (int kt=0; kt<nk; kt++){
    __syncthreads();
    if (kt+1 < nk) stageAB(buf^1, kt+1);
    bf16x8 af[4], bf[4];
    #pragma unroll
    for (int mt=0;mt<4;mt++) af[mt] = *(const bf16x8*)&Asl[buf][wm*64+mt*16+li][g*8];
    #pragma unroll
    for (int nt=0;nt<4;nt++) bf[nt] = *(const bf16x8*)&Bsl[buf][wn*64+nt*16+li][g*8];
    #pragma unroll
    for (int mt=0;mt<4;mt++)
      #pragma unroll
      for (int nt=0;nt<4;nt++)
        acc[mt][nt] = MFMA16(af[mt], bf[nt], acc[mt][nt]);
    buf ^= 1;
  }
  #pragma unroll
  for (int mt=0;mt<4;mt++){
    #pragma unroll
    for (int nt=0;nt<4;nt++){
      #pragma unroll
      for (int r=0;r<4;r++){
        const int row = i0 + wm*64 + mt*16 + g*4 + r;
        const int col = j0 + wn*64 + nt*16 + li;
        C[(size_t)row*N + col] = acc[mt][nt][r];
      }
    }
  }
}

// ---------------- depthwise causal conv (K=4) + silu ----------------
__global__ __launch_bounds__(256) void conv_silu(
    const float* __restrict__ x, const float* __restrict__ w, float* __restrict__ y)
{
  const int idx = blockIdx.x*256 + threadIdx.x;
  const int c = idx & (DMOD-1);
  const int i = idx >> 10;
  float4 wc = *(const float4*)(w + (size_t)c*4);
  float acc = wc.w * x[idx];
  if (i >= 1) acc += wc.z * x[idx -   DMOD];
  if (i >= 2) acc += wc.y * x[idx - 2*DMOD];
  if (i >= 3) acc += wc.x * x[idx - 3*DMOD];
  y[idx] = acc * sigf(acc);
}

// ---------------- beta (sigmoid) + 5-way gate probs per row ----------------
__global__ __launch_bounds__(256) void beta_gate(
    const float* __restrict__ hidden, const float* __restrict__ Wb,
    const float* __restrict__ gw, const float* __restrict__ gb,
    const float* __restrict__ logtemp, const float* __restrict__ epsp,
    float* __restrict__ betab, float* __restrict__ probs)
{
  const int i = blockIdx.x, t = threadIdx.x;
  float4 h4 = *(const float4*)(hidden + (size_t)i*DMOD + t*4);
  float part[24];
  #pragma unroll
  for (int o=0;o<24;o++){
    const float* wr = (o<4) ? (Wb + (size_t)o*DMOD) : (gw + (size_t)(o-4)*DMOD);
    float4 w4 = *(const float4*)(wr + t*4);
    part[o] = h4.x*w4.x + h4.y*w4.y + h4.z*w4.z + h4.w*w4.w;
  }
  __shared__ float red[24][4];
  __shared__ float fin[24];
  const int lane = t & 63, wv = t >> 6;
  #pragma unroll
  for (int o=0;o<24;o++){
    float vv = part[o];
    #pragma unroll
    for (int m=1;m<64;m<<=1) vv += __shfl_xor(vv, m, 64);
    if (lane == 0) red[o][wv] = vv;
  }
  __syncthreads();
  if (t < 24) fin[t] = red[t][0]+red[t][1]+red[t][2]+red[t][3];
  __syncthreads();
  if (t < NH){
    const int hh = t;
    betab[(size_t)i*NH + hh] = sigf(fin[hh]);
    float temp = expf(logtemp[hh]);
    float lg[5], mx = -1e30f;
    #pragma unroll
    for (int p=0;p<5;p++){ lg[p] = (fin[4+hh*5+p] + gb[hh*5+p]) / temp; mx = fmaxf(mx, lg[p]); }
    float ex[5], s = 0.f;
    #pragma unroll
    for (int p=0;p<5;p++){ ex[p] = expf(lg[p]-mx); s += ex[p]; }
    float eps = fminf(fmaxf(epsp[hh], 0.f), 0.2f);
    #pragma unroll
    for (int p=0;p<5;p++) probs[((size_t)i*NH+hh)*5 + p] = (ex[p]/s)*(1.f-5.f*eps) + eps;
  }
}

// ---------------- delta precompute: per (chunk, head) ----------------
// emits bf16 MFMA-ready operands: q,-w row-major XOR-swizzled (bits 3..5 by row&7),
// kT/attn XOR-swizzled (bits 3..4 by row&3), u fp32.
__global__ __launch_bounds__(256) void delta_pre(
    const float* __restrict__ q, const float* __restrict__ k, const float* __restrict__ v,
    const float* __restrict__ beta,
    u16* __restrict__ qbg, u16* __restrict__ wng, u16* __restrict__ kTg,
    u16* __restrict__ atg, float* __restrict__ ubuf)
{
  const int n = blockIdx.x, h = blockIdx.y;
  const int t = threadIdx.x;
  __shared__ float q_s[32][CPAD], k_s[32][CPAD], v_s[32][CPAD];
  __shared__ float T_s[32][32], Tb_s[32][32], M_s[32][32];
  __shared__ float rr[2][32][8];
  __shared__ float scl[2][32];
  __shared__ float bet_s[32];

  const int row = t >> 3, cq = t & 7;
  const size_t gb = (size_t)(n*32+row)*DMOD + h*DH + cq*32;
  const size_t cb = (size_t)(h*NCH+n)*32*256;
  const int sw = (row & 7) << 3;               // swizzle for q/w (256-col rows)
  float psq = 0.f, psk = 0.f;
  #pragma unroll
  for (int x=0;x<8;x++){
    float4 qa = *(const float4*)(q + gb + x*4);
    float4 ka = *(const float4*)(k + gb + x*4);
    float4 va = *(const float4*)(v + gb + x*4);
    *(float4*)&q_s[row][cq*32+x*4] = qa;
    *(float4*)&k_s[row][cq*32+x*4] = ka;
    *(float4*)&v_s[row][cq*32+x*4] = va;
    psq += qa.x*qa.x+qa.y*qa.y+qa.z*qa.z+qa.w*qa.w;
    psk += ka.x*ka.x+ka.y*ka.y+ka.z*ka.z+ka.w*ka.w;
  }
  rr[0][row][cq] = psq; rr[1][row][cq] = psk;
  if (t < 32) bet_s[t] = beta[(size_t)(n*32+t)*NH + h];
  __syncthreads();
  if (t < 64){
    const int wh = t >> 5, r = t & 31;
    float s = 1e-6f;
    #pragma unroll
    for (int x=0;x<8;x++) s += rr[wh][r][x];
    scl[wh][r] = rsqrtf(s);
  }
  __syncthreads();
  {
    const float sq = scl[0][row], sk2 = scl[1][row];
    #pragma unroll
    for (int x=0;x<8;x++){
      float4 qa = *(float4*)&q_s[row][cq*32+x*4];
      qa.x*=sq; qa.y*=sq; qa.z*=sq; qa.w*=sq;
      *(float4*)&q_s[row][cq*32+x*4] = qa;
      *(uint2*)&qbg[cb + (size_t)row*256 + ((cq*32 + x*4) ^ sw)] =
          make_uint2(pk2(qa.x,qa.y), pk2(qa.z,qa.w));
      float4 ka = *(float4*)&k_s[row][cq*32+x*4];
      ka.x*=sk2; ka.y*=sk2; ka.z*=sk2; ka.w*=sk2;
      *(float4*)&k_s[row][cq*32+x*4] = ka;
    }
  }
  __syncthreads();
  // kT bf16 [dk=256][c=32], u32-col swizzle: c2 ^ ((row&3)<<2)
  {
    unsigned* kp = (unsigned*)(kTg + ((size_t)(h*NCH+n)*256 + t)*32);
    #pragma unroll
    for (int c2=0;c2<16;c2++)
      kp[c2 ^ ((t&3)<<2)] = pk2(k_s[2*c2][t], k_s[2*c2+1][t]);
  }
  // M matrix
  {
    const int c = t >> 3, m0 = (t & 7)*4;
    float d0=0.f,d1=0.f,d2=0.f,d3=0.f;
    for (int kk=0;kk<DH;kk+=4){
      float4 a  = *(const float4*)&k_s[c][kk];
      float4 b0 = *(const float4*)&k_s[m0+0][kk];
      float4 b1 = *(const float4*)&k_s[m0+1][kk];
      float4 b2 = *(const float4*)&k_s[m0+2][kk];
      float4 b3 = *(const float4*)&k_s[m0+3][kk];
      d0 += a.x*b0.x + a.y*b0.y + a.z*b0.z + a.w*b0.w;
      d1 += a.x*b1.x + a.y*b1.y + a.z*b1.z + a.w*b1.w;
      d2 += a.x*b2.x + a.y*b2.y + a.z*b2.z + a.w*b2.w;
      d3 += a.x*b3.x + a.y*b3.y + a.z*b3.z + a.w*b3.w;
    }
    const float bc = bet_s[c];
    M_s[c][m0+0] = (m0+0 < c) ? bc*d0 : ((m0+0==c)?1.f:0.f);
    M_s[c][m0+1] = (m0+1 < c) ? bc*d1 : ((m0+1==c)?1.f:0.f);
    M_s[c][m0+2] = (m0+2 < c) ? bc*d2 : ((m0+2==c)?1.f:0.f);
    M_s[c][m0+3] = (m0+3 < c) ? bc*d3 : ((m0+3==c)?1.f:0.f);
  }
  __syncthreads();
  if (t < 32){
    const int j = t;
    for (int c=0;c<32;c++){
      float s = (c==j) ? 1.f : 0.f;
      for (int m=0;m<c;m++) s -= M_s[c][m]*T_s[m][j];
      T_s[c][j] = s;
    }
  }
  __syncthreads();
  {
    const int c = t >> 3, m0 = (t & 7)*4;
    #pragma unroll
    for (int x=0;x<4;x++) Tb_s[c][m0+x] = T_s[c][m0+x]*bet_s[m0+x];
  }
  __syncthreads();
  // w = Tb @ k_s (emit -w bf16, swizzled); u = Tb @ v_s (fp32)
  {
    const int colb = (t & 7)*4;
    float4 aw[8] = {};
    float4 au[8] = {};
    for (int m=0;m<32;m++){
      const float tb = Tb_s[row][m];
      #pragma unroll
      for (int y=0;y<8;y++){
        float4 kv = *(const float4*)&k_s[m][colb + y*32];
        float4 vv = *(const float4*)&v_s[m][colb + y*32];
        aw[y].x += tb*kv.x; aw[y].y += tb*kv.y; aw[y].z += tb*kv.z; aw[y].w += tb*kv.w;
        au[y].x += tb*vv.x; au[y].y += tb*vv.y; au[y].z += tb*vv.z; au[y].w += tb*vv.w;
      }
    }
    const size_t ob = (size_t)(n*32+row)*DMOD + h*DH + colb;
    #pragma unroll
    for (int y=0;y<8;y++){
      *(uint2*)&wng[cb + (size_t)row*256 + ((colb + y*32) ^ sw)] =
          make_uint2(pk2(-aw[y].x,-aw[y].y), pk2(-aw[y].z,-aw[y].w));
      *(float4*)(ubuf + ob + y*32) = au[y];
    }
  }
  // attn = tril(q k^T) bf16 [c][c'], u16-idx swizzle m0 ^ ((c&3)<<3)
  {
    const int c = t >> 3, m0 = (t & 7)*4;
    float d0=0.f,d1=0.f,d2=0.f,d3=0.f;
    for (int kk=0;kk<DH;kk+=4){
      float4 a  = *(const float4*)&q_s[c][kk];
      float4 b0 = *(const float4*)&k_s[m0+0][kk];
      float4 b1 = *(const float4*)&k_s[m0+1][kk];
      float4 b2 = *(const float4*)&k_s[m0+2][kk];
      float4 b3 = *(const float4*)&k_s[m0+3][kk];
      d0 += a.x*b0.x + a.y*b0.y + a.z*b0.z + a.w*b0.w;
      d1 += a.x*b1.x + a.y*b1.y + a.z*b1.z + a.w*b1.w;
      d2 += a.x*b2.x + a.y*b2.y + a.z*b2.z + a.w*b2.w;
      d3 += a.x*b3.x + a.y*b3.y + a.z*b3.z + a.w*b3.w;
    }
    d0 = (m0+0 <= c) ? d0 : 0.f;
    d1 = (m0+1 <= c) ? d1 : 0.f;
    d2 = (m0+2 <= c) ? d2 : 0.f;
    d3 = (m0+3 <= c) ? d3 : 0.f;
    *(uint2*)&atg[((size_t)(h*NCH+n)*32 + c)*32 + (m0 ^ ((c&3)<<3))] =
        make_uint2(pk2(d0,d1), pk2(d2,d3));
  }
}

// ---------------- fused delta scan v4: 4 waves (c-half x dk-half split) ----------------
// grid (16 dv-slices, 4 heads) x 256 thr. Wave (cs,ks): ua/q@S partials for c-half cs
// over dk-half ks. cs==0 waves own S[dk-half ks][dv16] in regs; cs==1 waves do attn@ua.
// Raw barriers with lgkmcnt-only waits; counted vmcnt(2); dbuf gload_lds staging.
__global__ __launch_bounds__(256) void delta_scan_fused(
    const u16* __restrict__ qbg, const u16* __restrict__ wng,
    const u16* __restrict__ kTg, const u16* __restrict__ atg,
    const float* __restrict__ ubuf, float* __restrict__ dob)
{
  const int qd = blockIdx.x, h = blockIdx.y;
  const int t = threadIdx.x, lane = t & 63, wv = t >> 6;
  const int cs = wv & 1, ks = wv >> 1;
  const int g = lane >> 4, li = lane & 15;
  const int swz = (li & 7) << 3;

  __shared__ __align__(16) unsigned char stg[2][53248];
  __shared__ __align__(16) u16 ST[16][264];
  __shared__ __align__(16) u16 uaT[16][40];
  __shared__ __align__(16) float pfu[2][2][64][4];   // [ks][cs][lane][4] (reused for q@S)
  __shared__ __align__(16) float pfat[2][64][4];     // [c-half][lane][4]

  f32x4 S[8];
  #pragma unroll
  for (int i=0;i<8;i++) S[i] = (f32x4){0.f,0.f,0.f,0.f};
  for (int i=t; i<16*264; i+=256) (&ST[0][0])[i] = 0;

  auto issue_stage = [&](int nn, int b){
    char* L = (char*)&stg[b][0];
    const size_t cbB = (size_t)(h*NCH+nn)*16384;
    #pragma unroll
    for (int j=0;j<13;j++){
      const int s = wv*13 + j;
      if (s < 48){
        const char* gsc = (s<16) ? (const char*)wng + cbB + (size_t)s*1024
                       : (s<32) ? (const char*)qbg + cbB + (size_t)(s-16)*1024
                                : (const char*)kTg + cbB + (size_t)(s-32)*1024;
        stage16(gsc + (size_t)lane*16, L + s*1024);
      } else if (s < 50){
        stage16((const char*)atg + (size_t)(h*NCH+nn)*2048 + (size_t)(s-48)*1024 + (size_t)lane*16,
                L + 49152 + (s-48)*1024);
      } else {
        const int i2 = s - 50;
        stage16(ubuf + (size_t)(nn*32 + i2*16 + (lane>>2))*DMOD + h*DH + qd*16 + (lane&3)*4,
                L + 51200 + i2*1024);
      }
    }
  };

  issue_stage(0, 0);

  for (int n=0;n<NCH;n++){
    const int b = n & 1;
    if (n == 0) asm volatile("s_waitcnt vmcnt(0)" ::: "memory");
    else        asm volatile("s_waitcnt vmcnt(2)" ::: "memory");
    asm volatile("s_waitcnt lgkmcnt(0)" ::: "memory");
    __builtin_amdgcn_s_barrier();                       // b1: buffer ready, ST ready
    __builtin_amdgcn_sched_barrier(0);
    issue_stage((n+1 < NCH) ? n+1 : NCH-1, b^1);

    const char* L = (const char*)&stg[b][0];
    const u16*  wl = (const u16*)(L);
    const u16*  ql = (const u16*)(L + 16384);
    const u16*  kl = (const u16*)(L + 32768);
    const u16*  al = (const u16*)(L + 49152);
    const float* ul = (const float*)(L + 51200);

    // ---- B-frags of S^T for own dk-half ----
    bf16x8 Bs[4];
    #pragma unroll
    for (int kb=0;kb<4;kb++)
      Bs[kb] = *(const bf16x8*)&ST[li][(ks*4+kb)*32 + g*8];

    // ---- partials: ua_p = -w@S (own quadrant), o_p = q@S ----
    f32x4 uap = (f32x4){0.f,0.f,0.f,0.f};
    f32x4 op  = (f32x4){0.f,0.f,0.f,0.f};
    #pragma unroll
    for (int kb=0;kb<4;kb++){
      const int idx = ((ks*4+kb)*32 + g*8) ^ swz;
      bf16x8 aw = *(const bf16x8*)&wl[(size_t)(cs*16+li)*256 + idx];
      bf16x8 aq = *(const bf16x8*)&ql[(size_t)(cs*16+li)*256 + idx];
      uap = MFMA16(aw, Bs[kb], uap);
      op  = MFMA16(aq, Bs[kb], op);
    }
    *(f32x4*)&pfu[ks][cs][lane][0] = uap;
    asm volatile("s_waitcnt lgkmcnt(0)" ::: "memory");
    __builtin_amdgcn_s_barrier();                       // b2: ua partials published
    __builtin_amdgcn_sched_barrier(0);

    // ---- reduce ua (redundant across ks pair) ----
    f32x4 ua;
    {
      f32x4 oth = *(const f32x4*)&pfu[ks^1][cs][lane][0];
      #pragma unroll
      for (int r=0;r<4;r++)
        ua[r] = uap[r] + oth[r] + ul[(cs*16 + g*4 + r)*16 + li];
    }
    if (ks == 0){
      *(unsigned*)&uaT[li][cs*16 + g*4]     = pk2(ua[0], ua[1]);
      *(unsigned*)&uaT[li][cs*16 + g*4 + 2] = pk2(ua[2], ua[3]);
    }
    asm volatile("s_waitcnt lgkmcnt(0)" ::: "memory");
    __builtin_amdgcn_s_barrier();                       // b3: uaT complete
    __builtin_amdgcn_sched_barrier(0);

    bf16x8 bu = *(const bf16x8*)&uaT[li][g*8];
    if (cs == 0){
      // ---- S += kT @ ua (own dk-half, 8 tiles) ----
      #pragma unroll
      for (int mtl=0;mtl<8;mtl++){
        const int row = (ks*8+mtl)*16 + li;
        const int idx = (g*8) ^ ((li&3)<<3);
        bf16x8 a = *(const bf16x8*)&kl[(size_t)row*32 + idx];
        S[mtl] = MFMA16(a, bu, S[mtl]);
      }
      // refresh own ST half (S_{n+1})
      #pragma unroll
      for (int mtl=0;mtl<8;mtl++)
        *(uint2*)&ST[li][(ks*8+mtl)*16 + g*4] =
            make_uint2(pk2(S[mtl][0],S[mtl][1]), pk2(S[mtl][2],S[mtl][3]));
    } else {
      // ---- attn @ ua for c-half ks ----
      const int idx = (g*8) ^ ((li&3)<<3);
      bf16x8 a = *(const bf16x8*)&al[(size_t)(ks*16+li)*32 + idx];
      f32x4 atp = (f32x4){0.f,0.f,0.f,0.f};
      atp = MFMA16(a, bu, atp);
      *(f32x4*)&pfat[ks][lane][0] = atp;
    }
    *(f32x4*)&pfu[ks][cs][lane][0] = op;                // publish q@S partial
    asm volatile("s_waitcnt lgkmcnt(0)" ::: "memory");
    __builtin_amdgcn_s_barrier();                       // b4: o partials complete
    __builtin_amdgcn_sched_barrier(0);

    // ---- o = q@S (both halves) + attn@ua ; each wave stores 2 rows ----
    {
      f32x4 oq = *(const f32x4*)&pfu[ks^1][cs][lane][0];
      f32x4 oa = *(const f32x4*)&pfat[cs][lane][0];
      const size_t ob = (size_t)(n*32 + cs*16)*DMOD + h*DH + qd*16 + li;
      #pragma unroll
      for (int r2=0;r2<2;r2++){
        const int r = ks*2 + r2;
        dob[ob + (size_t)(g*4+r)*DMOD] = op[r] + oq[r] + oa[r];
      }
    }
  }
}

// ---------------- transpose FIR filters to [j][c] ----------------
__global__ void prep_fir(const float* __restrict__ fs, const float* __restrict__ fm,
                         const float* __restrict__ fl, float* __restrict__ fts,
                         float* __restrict__ ftm, float* __restrict__ ftl)
{
  const int idx = blockIdx.x*256 + threadIdx.x;
  if (idx < 63*1024){
    const int j = idx >> 10, c = idx & 1023;
    ftl[idx] = fl[(size_t)c*63 + j];
  } else if (idx < 78*1024){
    const int r = idx - 63*1024;
    const int j = r >> 10, c = r & 1023;
    ftm[r] = fm[(size_t)c*15 + j];
  } else {
    const int r = idx - 78*1024;
    const int j = r >> 10, c = r & 1023;
    fts[r] = fs[(size_t)c*3 + j];
  }
}

// ---------------- FIR convs + gated mix + per-head RMSNorm (bf16 out) ----------------
__global__ __launch_bounds__(256) void fir_mix(
    const float* __restrict__ v, const float* __restrict__ dout,
    const float* __restrict__ probs, const float* __restrict__ ftl,
    const float* __restrict__ ftm, const float* __restrict__ fts,
    const float* __restrict__ normw, u16* __restrict__ omixb)
{
  const int i = blockIdx.x, h = blockIdx.y, dv = threadIdx.x;
  const int c = h*DH + dv;
  float accl = 0.f, accm = 0.f, accs = 0.f;
  {
    const int js = (i >= 62) ? 0 : (62 - i);
    for (int j=js;j<63;j++)
      accl += v[(size_t)(i-62+j)*DMOD + c] * ftl[(size_t)j*DMOD + c];
  }
  {
    const int js = (i >= 14) ? 0 : (14 - i);
    for (int j=js;j<15;j++)
      accm += v[(size_t)(i-14+j)*DMOD + c] * ftm[(size_t)j*DMOD + c];
  }
  {
    const int js = (i >= 2) ? 0 : (2 - i);
    for (int j=js;j<3;j++)
      accs += v[(size_t)(i-2+j)*DMOD + c] * fts[(size_t)j*DMOD + c];
  }
  const float* pr = probs + ((size_t)i*NH + h)*5;
  const float dvv = dout[(size_t)i*DMOD + c];
  const float vv  = v[(size_t)i*DMOD + c];
  float mix = pr[0]*accs + pr[1]*accm + pr[2]*accl + pr[3]*dvv + pr[4]*vv;
  float ss = mix*mix;
  #pragma unroll
  for (int m=1;m<64;m<<=1) ss += __shfl_xor(ss, m, 64);
  __shared__ float pr4[4];
  if ((threadIdx.x & 63) == 0) pr4[threadIdx.x >> 6] = ss;
  __syncthreads();
  const float tot = pr4[0]+pr4[1]+pr4[2]+pr4[3];
  const float o = mix * rsqrtf(tot*(1.f/256.f) + 1e-5f) * normw[dv];
  omixb[(size_t)i*DMOD + c] = f2bf(o);
}

// ---------------- launch ----------------
extern "C" void kernel_launch(void* const* d_in, const int* in_sizes, int n_in,
                              void* d_out, int out_size, void* d_ws, size_t ws_size,
                              hipStream_t stream)
{
  const float* hidden = (const float*)d_in[0];
  const float* Wq     = (const float*)d_in[1];
  const float* Wk     = (const float*)d_in[2];
  const float* Wv     = (const float*)d_in[3];
  const float* Wb     = (const float*)d_in[4];
  const float* convq  = (const float*)d_in[5];
  const float* convk  = (const float*)d_in[6];
  const float* convv  = (const float*)d_in[7];
  const float* firs   = (const float*)d_in[8];
  const float* firm   = (const float*)d_in[9];
  const float* firl   = (const float*)d_in[10];
  const float* gatew  = (const float*)d_in[11];
  const float* gateb  = (const float*)d_in[12];
  const float* logtemp= (const float*)d_in[13];
  const float* epsp   = (const float*)d_in[14];
  const float* normw  = (const float*)d_in[15];
  const float* Wo     = (const float*)d_in[16];
  float* out = (float*)d_out;

  char* W = (char*)d_ws;
  const size_t MB = (size_t)1 << 20;
  float* tmp   = (float*)(W + 0*MB);         // 8MB: pre-conv GEMM out; later u
  float* qb    = (float*)(W + 8*MB);         // 8MB; dob aliases after delta_pre
  float* dob   = (float*)(W + 8*MB);
  float* kb    = (float*)(W + 16*MB);        // 8MB; omixb aliases after delta_pre
  u16*   omixb = (u16*)  (W + 16*MB);
  float* vb    = (float*)(W + 24*MB);        // 8MB
  u16*   hidb  = (u16*)  (W + 32*MB);        // 4MB
  u16*   wqb   = (u16*)  (W + 36*MB);        // 2MB
  u16*   wkb   = (u16*)  (W + 38*MB);        // 2MB
  u16*   wvb   = (u16*)  (W + 40*MB);        // 2MB
  u16*   wob   = (u16*)  (W + 42*MB);        // 2MB
  u16*   qbg   = (u16*)  (W + 44*MB);        // 4MB
  u16*   wng   = (u16*)  (W + 48*MB);        // 4MB
  u16*   kTg   = (u16*)  (W + 52*MB);        // 4MB
  u16*   atg   = (u16*)  (W + 56*MB);        // 0.5MB
  float* betab = (float*)(W + 56*MB + 524288);            // 32KB
  float* probs = (float*)(W + 56*MB + 524288 + 32768);    // 160KB
  float* ftl   = (float*)(W + 57*MB);                     // 252KB
  float* ftm   = (float*)(W + 57*MB + 300*1024);          // 60KB
  float* fts   = (float*)(W + 57*MB + 380*1024);          // 12KB

  cvt_bf16<<<2048, 256, 0, stream>>>(hidden, hidb, 2048*1024/4);
  cvt_bf16<<<1024, 256, 0, stream>>>(Wq, wqb, 1024*1024/4);
  cvt_bf16<<<1024, 256, 0, stream>>>(Wk, wkb, 1024*1024/4);
  cvt_bf16<<<1024, 256, 0, stream>>>(Wv, wvb, 1024*1024/4);
  cvt_bf16<<<1024, 256, 0, stream>>>(Wo, wob, 1024*1024/4);
  prep_fir<<<324, 256, 0, stream>>>(firs, firm, firl, fts, ftm, ftl);

  gemm_bf16<<<dim3(16,8), 256, 0, stream>>>(hidb, wqb, tmp, LSEQ, DMOD, DMOD);
  conv_silu<<<8192, 256, 0, stream>>>(tmp, convq, qb);
  gemm_bf16<<<dim3(16,8), 256, 0, stream>>>(hidb, wkb, tmp, LSEQ, DMOD, DMOD);
  conv_silu<<<8192, 256, 0, stream>>>(tmp, convk, kb);
  gemm_bf16<<<dim3(16,8), 256, 0, stream>>>(hidb, wvb, tmp, LSEQ, DMOD, DMOD);
  conv_silu<<<8192, 256, 0, stream>>>(tmp, convv, vb);

  beta_gate<<<2048, 256, 0, stream>>>(hidden, Wb, gatew, gateb, logtemp, epsp, betab, probs);

  delta_pre<<<dim3(64,4), 256, 0, stream>>>(qb, kb, vb, betab, qbg, wng, kTg, atg, tmp);
  delta_scan_fused<<<dim3(16,4), 256, 0, stream>>>(qbg, wng, kTg, atg, tmp, dob);

  fir_mix<<<dim3(2048,4), 256, 0, stream>>>(vb, dob, probs, ftl, ftm, fts, normw, omixb);

  gemm_bf16<<<dim3(16,8), 256, 0, stream>>>(omixb, wob, out, LSEQ, DMOD, DMOD);
}